// Round 3
// baseline (445.005 us; speedup 1.0000x reference)
//
#include <hip/hip_runtime.h>
#include <hip/hip_bf16.h>
#include <hip/hip_cooperative_groups.h>

namespace cg = cooperative_groups;

// GCN 2-layer, 5 launches.
//   preproc (cooperative, nbuck blocks):
//     A: bucket histogram + edge_index copy-out + W1/W2 transpose->bf16
//     B: per-bucket exclusive scan of per-partition counts (+totals)
//     C: partition edges into bucket-contiguous ebuf
//     D: per-bucket counting sort -> csr(ushort), rowptr, dis
//     E: xconv Xhs = bf16(dis*X) [N][128] (zero-padded 89->128)
//   gather   : agg = bf16( rows_i + sum_s rows_s )  -- 2 rows per VMEM inst
//   gemm1    : g2h   = bf16( relu(d*(agg1h@W1t) + b1) * d )  (MFMA, no LDS)
//   gather   : agg2h
//   gemm2    : out   = relu( d*(agg2h@W2t) + b2 )            fp32
// All row operands bf16 (fp32 accumulation). Requires N < 65536.

#define HID 128
#define KIN 89
#define KP 128    // padded input dim (unified 256B rows, same as HID)
#define BSH 7     // bucket = 128 nodes
#define BNODES 128
#define MAXBUCK 512   // capacity of bucket-indexed arrays (histG stride)
#define P4CAP 3072    // staging capacity per bucket (mean ~2046, 5sd ~2270)

typedef __attribute__((ext_vector_type(8))) short bf16x8;
typedef __attribute__((ext_vector_type(4))) float f32x4;

static __device__ inline float2 unpack_bf16(unsigned v) {
    union { unsigned u; float f; } lo, hi;
    lo.u = v << 16;
    hi.u = v & 0xFFFF0000u;
    return make_float2(lo.f, hi.f);
}

static __device__ inline unsigned pack_bf16(float a, float b) {
    __hip_bfloat162 h = __float22bfloat162_rn(make_float2(a, b));
    return *reinterpret_cast<unsigned*>(&h);
}

static __device__ inline unsigned short f2bf(float v) {
    __hip_bfloat16 h = __float2bfloat16(v);
    return *reinterpret_cast<unsigned short*>(&h);
}

// In-block exclusive scan of totals[0..nbuck), nbuck <= 512, 256 threads.
static __device__ inline void scan_totals2(const int* __restrict__ totals,
                                           int* __restrict__ sexcl,
                                           int* __restrict__ wsum,
                                           int nbuck, int tid)
{
    const int lane = tid & 63, wid = tid >> 6;
    const int i0 = 2 * tid, i1 = 2 * tid + 1;
    int t0 = (i0 < nbuck) ? totals[i0] : 0;
    int t1 = (i1 < nbuck) ? totals[i1] : 0;
    int p = t0 + t1;
    int s = p;
#pragma unroll
    for (int off = 1; off < 64; off <<= 1) {
        int t = __shfl_up(s, off, 64);
        if (lane >= off) s += t;
    }
    if (lane == 63) wsum[wid] = s;
    __syncthreads();
    if (tid == 0) {
        int a = 0;
#pragma unroll
        for (int w = 0; w < 4; ++w) { int t = wsum[w]; wsum[w] = a; a += t; }
    }
    __syncthreads();
    int excl = wsum[wid] + s - p;
    sexcl[i0] = excl;
    sexcl[i1] = excl + t0;
}

// ---- preproc: fused p1+p2a+p3+p4+xconv, cooperative grid of nbuck blocks ----
__global__ __launch_bounds__(256) void preproc_kernel(
    const int* __restrict__ ei, float* __restrict__ outE,
    const float* __restrict__ X,
    const float* __restrict__ W1, unsigned short* __restrict__ W1t,
    const float* __restrict__ W2, unsigned short* __restrict__ W2t,
    int* __restrict__ histG, int* __restrict__ totals,
    int* __restrict__ rowptr, float* __restrict__ dis,
    unsigned* __restrict__ ebuf, unsigned short* __restrict__ csr,
    unsigned* __restrict__ Xhs,
    int N, int E, int nbuck)
{
    __shared__ int sA[MAXBUCK];          // hist / bucket-base / cur
    __shared__ int wsum[4];
    __shared__ int counts[BNODES];
    __shared__ int cursor[BNODES];
    __shared__ int w2[2];
    __shared__ unsigned short staging[P4CAP];

    cg::grid_group grid = cg::this_grid();
    const int tid = threadIdx.x, blk = blockIdx.x;
    const int npart = gridDim.x;                 // == nbuck
    const int* src = ei;
    const int* dst = ei + E;
    const int chunk = (E + npart - 1) / npart;
    const int beg = blk * chunk, end = min(beg + chunk, E);
    const int lane = tid & 63, wid = tid >> 6;

    // ---- Phase A: histogram + edge copy + weight transposes ----
    for (int b = tid; b < nbuck; b += 256) sA[b] = 0;

    int tg = blk * 256 + tid;
    if (tg < HID * KP) {
        int n = tg / KP, k = tg % KP;
        W1t[tg] = f2bf(k < KIN ? W1[(size_t)k * HID + n] : 0.0f);
    } else {
        int t2 = tg - HID * KP;
        if (t2 < HID * HID) {
            int n = t2 / HID, k = t2 % HID;
            W2t[t2] = f2bf(W2[(size_t)k * HID + n]);
        }
    }
    __syncthreads();

    for (int i = beg + tid; i < end; i += 256) {
        int d = dst[i];
        atomicAdd(&sA[d >> BSH], 1);
        outE[i] = (float)src[i];
        outE[E + i] = (float)d;
    }
    __syncthreads();
    for (int b = tid; b < nbuck; b += 256) histG[(size_t)b * MAXBUCK + blk] = sA[b];

    grid.sync();

    // ---- Phase B: scan this block's bucket row (npart counts) ----
    {
        int* row = histG + (size_t)blk * MAXBUCK;
        const int i0 = 2 * tid, i1 = i0 + 1;
        int t0 = (i0 < npart) ? row[i0] : 0;
        int t1 = (i1 < npart) ? row[i1] : 0;
        int p = t0 + t1;
        int s = p;
#pragma unroll
        for (int off = 1; off < 64; off <<= 1) {
            int t = __shfl_up(s, off, 64);
            if (lane >= off) s += t;
        }
        if (lane == 63) wsum[wid] = s;
        __syncthreads();
        if (tid == 0) {
            int a = 0;
#pragma unroll
            for (int w = 0; w < 4; ++w) { int t = wsum[w]; wsum[w] = a; a += t; }
            totals[blk] = a;             // grand total of this bucket
        }
        __syncthreads();
        int excl = wsum[wid] + s - p;
        if (i0 < npart) row[i0] = excl;
        if (i1 < npart) row[i1] = excl + t0;
    }

    grid.sync();

    // ---- Phase C: partition edges into bucket-contiguous ebuf ----
    scan_totals2(totals, sA, wsum, nbuck, tid);  // sA[b] = bucket base
    __syncthreads();
    for (int b = tid; b < nbuck; b += 256) sA[b] += histG[(size_t)b * MAXBUCK + blk];
    __syncthreads();
    for (int i = beg + tid; i < end; i += 256) {
        int d = dst[i];
        int b = d >> BSH;
        int pos = atomicAdd(&sA[b], 1);
        ebuf[pos] = ((unsigned)(d & (BNODES - 1)) << 16) | (unsigned)src[i];
    }

    grid.sync();

    // ---- Phase D: per-bucket counting sort -> csr, rowptr, dis ----
    scan_totals2(totals, sA, wsum, nbuck, tid);
    __syncthreads();
    const int gbase = sA[blk];
    const int cnt = totals[blk];

    if (tid < BNODES) counts[tid] = 0;
    __syncthreads();
    for (int i = tid; i < cnt; i += 256)
        atomicAdd(&counts[ebuf[gbase + i] >> 16], 1);
    __syncthreads();

    // exclusive scan of BNODES=128 counts (first 2 waves)
    int c = 0, s = 0;
    if (tid < BNODES) {
        c = counts[tid];
        s = c;
#pragma unroll
        for (int off = 1; off < 64; off <<= 1) {
            int t = __shfl_up(s, off, 64);
            if (lane >= off) s += t;
        }
        if (lane == 63) w2[wid] = s;
    }
    __syncthreads();
    if (tid == 0) { int t = w2[0]; w2[0] = 0; w2[1] = t; }
    __syncthreads();
    if (tid < BNODES) {
        int excl = w2[wid] + s - c;
        cursor[tid] = excl;
        int node = blk * BNODES + tid;
        if (node < N) {
            rowptr[node] = gbase + excl;
            dis[node] = rsqrtf(1.0f + (float)c);
        }
    }
    if (blk == 0 && tid == 0) rowptr[N] = E;
    __syncthreads();

    if (cnt <= P4CAP) {
        for (int i = tid; i < cnt; i += 256) {
            unsigned v = ebuf[gbase + i];
            int pos = atomicAdd(&cursor[v >> 16], 1);
            staging[pos] = (unsigned short)(v & 0xFFFFu);
        }
        __syncthreads();
        for (int i = tid; i < cnt; i += 256)
            csr[gbase + i] = staging[i];
    } else {
        for (int i = tid; i < cnt; i += 256) {
            unsigned v = ebuf[gbase + i];
            int pos = atomicAdd(&cursor[v >> 16], 1);
            csr[gbase + pos] = (unsigned short)(v & 0xFFFFu);
        }
    }

    grid.sync();

    // ---- Phase E: xconv Xhs = bf16(dis*X), zero-padded cols 89..127 ----
    const int totalw = N * (KP / 2);
    for (int t = blk * 256 + tid; t < totalw; t += npart * 256) {
        int n = t / (KP / 2), cc = t % (KP / 2);
        float d = dis[n];
        const float* xr = X + (size_t)n * KIN;
        float a = (2 * cc     < KIN) ? d * xr[2 * cc]     : 0.0f;
        float b = (2 * cc + 1 < KIN) ? d * xr[2 * cc + 1] : 0.0f;
        Xhs[t] = pack_bf16(a, b);
    }
}

// ---- gather: one wave per node, 2 rows per VMEM inst (paired halves) ----
// rows are [N][32] uint2 (=256B bf16 rows). Lanes 0-31 take even-list rows,
// lanes 32-63 odd-list rows; cross-half combine via shfl_xor(32) at the end.
__global__ __launch_bounds__(256) void gather_kernel(
    const uint2* __restrict__ rows, const int* __restrict__ rowptr,
    const unsigned short* __restrict__ csr, uint2* __restrict__ aggh, int N)
{
    int node = blockIdx.x * 4 + (threadIdx.x >> 6);
    if (node >= N) return;
    const int lane = threadIdx.x & 63;
    const int half = lane >> 5;
    const int sl   = lane & 31;

    float a0 = 0.0f, a1 = 0.0f, a2 = 0.0f, a3 = 0.0f;
    if (half == 0) {                       // self row, added once
        uint2 sv = rows[(size_t)node * 32 + sl];
        float2 lo = unpack_bf16(sv.x), hi = unpack_bf16(sv.y);
        a0 = lo.x; a1 = lo.y; a2 = hi.x; a3 = hi.y;
    }

    const int beg = rowptr[node], end = rowptr[node + 1];
    int j = beg;
    for (; j + 8 <= end; j += 8) {         // 8 edges: 4 paired loads
        int r0 = csr[j     + half];
        int r1 = csr[j + 2 + half];
        int r2 = csr[j + 4 + half];
        int r3 = csr[j + 6 + half];
        uint2 v0 = rows[(size_t)r0 * 32 + sl];
        uint2 v1 = rows[(size_t)r1 * 32 + sl];
        uint2 v2 = rows[(size_t)r2 * 32 + sl];
        uint2 v3 = rows[(size_t)r3 * 32 + sl];
        float2 p;
        p = unpack_bf16(v0.x); a0 += p.x; a1 += p.y;
        p = unpack_bf16(v0.y); a2 += p.x; a3 += p.y;
        p = unpack_bf16(v1.x); a0 += p.x; a1 += p.y;
        p = unpack_bf16(v1.y); a2 += p.x; a3 += p.y;
        p = unpack_bf16(v2.x); a0 += p.x; a1 += p.y;
        p = unpack_bf16(v2.y); a2 += p.x; a3 += p.y;
        p = unpack_bf16(v3.x); a0 += p.x; a1 += p.y;
        p = unpack_bf16(v3.y); a2 += p.x; a3 += p.y;
    }
    for (; j + 4 <= end; j += 4) {         // 4 edges: 2 paired loads
        int r0 = csr[j     + half];
        int r1 = csr[j + 2 + half];
        uint2 v0 = rows[(size_t)r0 * 32 + sl];
        uint2 v1 = rows[(size_t)r1 * 32 + sl];
        float2 p;
        p = unpack_bf16(v0.x); a0 += p.x; a1 += p.y;
        p = unpack_bf16(v0.y); a2 += p.x; a3 += p.y;
        p = unpack_bf16(v1.x); a0 += p.x; a1 += p.y;
        p = unpack_bf16(v1.y); a2 += p.x; a3 += p.y;
    }
    for (; j < end; j += 2) {              // tail: 1-2 edges, predicated
        int idx = j + half;
        if (idx < end) {
            int r = csr[idx];
            uint2 v = rows[(size_t)r * 32 + sl];
            float2 lo = unpack_bf16(v.x), hi = unpack_bf16(v.y);
            a0 += lo.x; a1 += lo.y; a2 += hi.x; a3 += hi.y;
        }
    }

    a0 += __shfl_xor(a0, 32, 64);
    a1 += __shfl_xor(a1, 32, 64);
    a2 += __shfl_xor(a2, 32, 64);
    a3 += __shfl_xor(a3, 32, 64);
    if (half == 0)
        aggh[(size_t)node * 32 + sl] =
            make_uint2(pack_bf16(a0, a1), pack_bf16(a2, a3));
}

// ---- MFMA GEMM (no LDS, transposed-D epilogue) ----
// Block = 64 nodes (4 waves x 16), wave covers 128 cols as 8 16x16 tiles.
//   LAYER1: store bf16( relu(d*acc + b) * d )     (pre-scaled rows for layer 2)
//   LAYER2: store fp32( relu(d*acc + b) )
template<int KPA, bool LAYER1>
__global__ __launch_bounds__(256) void mfma_gemm_kernel(
    const unsigned short* __restrict__ A, const unsigned short* __restrict__ Wt,
    const float* __restrict__ bias, const float* __restrict__ dis,
    void* __restrict__ outp, int N)
{
    const int wave = threadIdx.x >> 6;
    const int lane = threadIdx.x & 63;
    const int m    = lane & 15;
    const int quad = lane >> 4;
    const int row0 = blockIdx.x * 64 + wave * 16;
    const int node = row0 + m;

    f32x4 acc[8];
#pragma unroll
    for (int t = 0; t < 8; ++t) acc[t] = (f32x4){0.0f, 0.0f, 0.0f, 0.0f};

    const int arow = min(node, N - 1);           // clamp: stores are guarded
    const unsigned short* arp = A + (size_t)arow * KPA;

#pragma unroll
    for (int c = 0; c < KPA / 32; ++c) {
        const int k0 = c * 32 + quad * 8;
        bf16x8 nv = *(const bf16x8*)(arp + k0);                      // B-frag
#pragma unroll
        for (int t = 0; t < 8; ++t) {
            bf16x8 wv = *(const bf16x8*)(Wt + (size_t)(t * 16 + m) * KPA + k0);  // A-frag
            acc[t] = __builtin_amdgcn_mfma_f32_16x16x32_bf16(wv, nv, acc[t], 0, 0, 0);
        }
    }

    if (node < N) {
        const float dv = dis[node];
#pragma unroll
        for (int t = 0; t < 8; ++t) {
            const int col0 = t * 16 + quad * 4;
            float4 bb = *(const float4*)&bias[col0];
            float r0 = fmaxf(fmaf(dv, acc[t][0], bb.x), 0.0f);
            float r1 = fmaxf(fmaf(dv, acc[t][1], bb.y), 0.0f);
            float r2 = fmaxf(fmaf(dv, acc[t][2], bb.z), 0.0f);
            float r3 = fmaxf(fmaf(dv, acc[t][3], bb.w), 0.0f);
            if (LAYER1) {
                uint2 u;
                u.x = pack_bf16(r0 * dv, r1 * dv);
                u.y = pack_bf16(r2 * dv, r3 * dv);
                *(uint2*)((unsigned short*)outp + (size_t)node * HID + col0) = u;
            } else {
                float4 r = make_float4(r0, r1, r2, r3);
                *(float4*)((float*)outp + (size_t)node * HID + col0) = r;
            }
        }
    }
}

// ---------------- launch ----------------

static inline char* wsal(char*& p, size_t n) {
    uintptr_t q = ((uintptr_t)p + 255) & ~(uintptr_t)255;
    char* r = (char*)q;
    p = r + n;
    return r;
}

extern "C" void kernel_launch(void* const* d_in, const int* in_sizes, int n_in,
                              void* d_out, int out_size, void* d_ws, size_t ws_size,
                              hipStream_t stream) {
    const float* x  = (const float*)d_in[0];
    const int*   ei = (const int*)d_in[1];
    const float* W1 = (const float*)d_in[2];
    const float* b1 = (const float*)d_in[3];
    const float* W2 = (const float*)d_in[4];
    const float* b2 = (const float*)d_in[5];

    int N = in_sizes[0] / KIN;  // 50000  (< 65536 required)
    int E = in_sizes[1] / 2;    // 800000
    int nbuck = (N + BNODES - 1) >> BSH;   // 391 (<= MAXBUCK)

    float* out  = (float*)d_out;
    float* outH = out;                      // [N,128] final fp32 output
    float* outE = out + (size_t)N * HID;    // [2,E] edge_index as float

    char* ws = (char*)d_ws;
    int*            histG  = (int*)wsal(ws, (size_t)MAXBUCK * MAXBUCK * 4);
    int*            totals = (int*)wsal(ws, MAXBUCK * 4);
    int*            rowptr = (int*)wsal(ws, (size_t)(N + 1) * 4);
    float*          dis    = (float*)wsal(ws, (size_t)N * 4);
    unsigned*       ebuf   = (unsigned*)wsal(ws, (size_t)E * 4);
    unsigned short* csr    = (unsigned short*)wsal(ws, (size_t)E * 2);
    unsigned*       Xhs    = (unsigned*)wsal(ws, (size_t)N * (KP / 2) * 4);
    unsigned*       agg1h  = (unsigned*)wsal(ws, (size_t)N * (KP / 2) * 4);
    unsigned short* g2h    = (unsigned short*)wsal(ws, (size_t)N * HID * 2);
    unsigned short* agg2h  = (unsigned short*)wsal(ws, (size_t)N * HID * 2);
    unsigned short* W1t    = (unsigned short*)wsal(ws, (size_t)HID * KP * 2);
    unsigned short* W2t    = (unsigned short*)wsal(ws, (size_t)HID * HID * 2);

    // fused preprocessing (cooperative: nbuck blocks, grid-wide syncs)
    {
        void* args[] = {
            (void*)&ei, (void*)&outE, (void*)&x,
            (void*)&W1, (void*)&W1t, (void*)&W2, (void*)&W2t,
            (void*)&histG, (void*)&totals, (void*)&rowptr, (void*)&dis,
            (void*)&ebuf, (void*)&csr, (void*)&Xhs,
            (void*)&N, (void*)&E, (void*)&nbuck
        };
        hipLaunchCooperativeKernel((const void*)preproc_kernel,
                                   dim3(nbuck), dim3(256), args, 0, stream);
    }

    const int ngt = (N + 3) / 4;
    const int ngm = (N + 63) / 64;

    // Layer 1
    gather_kernel<<<ngt, 256, 0, stream>>>((const uint2*)Xhs, rowptr, csr,
                                           (uint2*)agg1h, N);
    mfma_gemm_kernel<KP, true><<<ngm, 256, 0, stream>>>(
        (const unsigned short*)agg1h, W1t, b1, dis, g2h, N);

    // Layer 2
    gather_kernel<<<ngt, 256, 0, stream>>>((const uint2*)g2h, rowptr, csr,
                                           (uint2*)agg2h, N);
    mfma_gemm_kernel<HID, false><<<ngm, 256, 0, stream>>>(
        agg2h, W2t, b2, dis, outH, N);
}

// Round 5
// 226.708 us; speedup vs baseline: 1.9629x; 1.9629x over previous
//
#include <hip/hip_runtime.h>
#include <hip/hip_bf16.h>

// GCN 2-layer, 9 launches. Buckets of 128 nodes (391 buckets).
//   p1    : bucket histogram + edge_index copy-out + W1/W2 transpose->bf16
//   p2a   : scan of per-partition bucket counts
//   p3    : partition edges into bucket-contiguous ebuf
//   p4    : per-bucket counting sort -> csr(ushort), rowptr, dis
//   xconv : Xhs = bf16(dis*X) [N][128] (zero-padded 89->128)
//   gather   : agg = bf16( rows_i + sum_s rows_s )  -- 4 nodes/wave, uint4 rows
//   gemm1    : g2h   = bf16( relu(d*(agg1h@W1t) + b1) * d )  (MFMA, no LDS)
//   gemm2    : out   = relu( d*(agg2h@W2t) + b2 )            fp32
// All row operands bf16 (fp32 accumulation). Requires N < 65536.

#define HID 128
#define KIN 89
#define KP 128    // padded input dim (unified 256B rows, same as HID)
#define BSH 7     // bucket = 128 nodes
#define BNODES 128
#define MAXBUCK 512   // capacity of bucket-indexed LDS/scan arrays
#define NPB 128       // partition blocks
#define P4CAP 3072    // staging capacity per bucket (mean ~2046, 5sd ~2270)

typedef __attribute__((ext_vector_type(8))) short bf16x8;
typedef __attribute__((ext_vector_type(4))) float f32x4;

static __device__ inline float2 unpack_bf16(unsigned v) {
    union { unsigned u; float f; } lo, hi;
    lo.u = v << 16;
    hi.u = v & 0xFFFF0000u;
    return make_float2(lo.f, hi.f);
}

static __device__ inline unsigned pack_bf16(float a, float b) {
    __hip_bfloat162 h = __float22bfloat162_rn(make_float2(a, b));
    return *reinterpret_cast<unsigned*>(&h);
}

static __device__ inline unsigned short f2bf(float v) {
    __hip_bfloat16 h = __float2bfloat16(v);
    return *reinterpret_cast<unsigned short*>(&h);
}

// ---- p1: histogram + edge copy + weight transposes ----
__global__ __launch_bounds__(256) void p1_kernel(
    const int* __restrict__ ei, float* __restrict__ outE,
    int* __restrict__ histG,
    const float* __restrict__ W1, unsigned short* __restrict__ W1t,
    const float* __restrict__ W2, unsigned short* __restrict__ W2t,
    int E, int nbuck)
{
    __shared__ int h[MAXBUCK];
    const int tid = threadIdx.x, blk = blockIdx.x;
    const int* src = ei;
    const int* dst = ei + E;
    for (int b = tid; b < nbuck; b += 256) h[b] = 0;

    // weight transposes spread over the grid's first 32768 threads
    int tg = blk * 256 + tid;
    if (tg < HID * KP) {
        int n = tg / KP, k = tg % KP;
        W1t[tg] = f2bf(k < KIN ? W1[(size_t)k * HID + n] : 0.0f);
    } else {
        int t2 = tg - HID * KP;
        if (t2 < HID * HID) {
            int n = t2 / HID, k = t2 % HID;
            W2t[t2] = f2bf(W2[(size_t)k * HID + n]);
        }
    }
    __syncthreads();

    const int chunk = (E + NPB - 1) / NPB;
    const int beg = blk * chunk, end = min(beg + chunk, E);
    for (int i = beg + tid; i < end; i += 256) {
        int d = dst[i];
        atomicAdd(&h[d >> BSH], 1);
        outE[i] = (float)src[i];
        outE[E + i] = (float)d;
    }
    __syncthreads();
    for (int b = tid; b < nbuck; b += 256) histG[b * NPB + blk] = h[b];
}

// ---- p2a: per-bucket exclusive scan of its NPB counts + totals ----
__global__ __launch_bounds__(NPB) void p2a_kernel(
    int* __restrict__ histG, int* __restrict__ totals)
{
    __shared__ int wsum[NPB / 64];
    const int b = blockIdx.x, tid = threadIdx.x, lane = tid & 63, wid = tid >> 6;
    int c = histG[b * NPB + tid];
    int s = c;
#pragma unroll
    for (int off = 1; off < 64; off <<= 1) {
        int t = __shfl_up(s, off, 64);
        if (lane >= off) s += t;
    }
    if (lane == 63) wsum[wid] = s;
    __syncthreads();
    if (tid == 0) {
        int a = 0;
#pragma unroll
        for (int w = 0; w < NPB / 64; ++w) { int t = wsum[w]; wsum[w] = a; a += t; }
    }
    __syncthreads();
    int excl = wsum[wid] + s - c;
    histG[b * NPB + tid] = excl;
    if (tid == NPB - 1) totals[b] = excl + c;
}

// In-block exclusive scan of totals[0..nbuck), nbuck <= 512, 256 threads.
static __device__ inline void scan_totals2(const int* __restrict__ totals,
                                           int* __restrict__ sexcl,
                                           int* __restrict__ wsum,
                                           int nbuck, int tid)
{
    const int lane = tid & 63, wid = tid >> 6;
    const int i0 = 2 * tid, i1 = 2 * tid + 1;
    int t0 = (i0 < nbuck) ? totals[i0] : 0;
    int t1 = (i1 < nbuck) ? totals[i1] : 0;
    int p = t0 + t1;
    int s = p;
#pragma unroll
    for (int off = 1; off < 64; off <<= 1) {
        int t = __shfl_up(s, off, 64);
        if (lane >= off) s += t;
    }
    if (lane == 63) wsum[wid] = s;
    __syncthreads();
    if (tid == 0) {
        int a = 0;
#pragma unroll
        for (int w = 0; w < 4; ++w) { int t = wsum[w]; wsum[w] = a; a += t; }
    }
    __syncthreads();
    int excl = wsum[wid] + s - p;
    sexcl[i0] = excl;
    sexcl[i1] = excl + t0;
}

// ---- p3: partition edges into bucket-contiguous ebuf ----
__global__ __launch_bounds__(256) void p3_part_kernel(
    const int* __restrict__ ei, const int* __restrict__ histG,
    const int* __restrict__ totals, unsigned* __restrict__ ebuf,
    int E, int nbuck)
{
    __shared__ int cur[MAXBUCK];
    __shared__ int wsum[4];
    const int tid = threadIdx.x, blk = blockIdx.x;
    const int* src = ei;
    const int* dst = ei + E;
    scan_totals2(totals, cur, wsum, nbuck, tid);   // cur[b] = bucket base
    __syncthreads();
    for (int b = tid; b < nbuck; b += 256) cur[b] += histG[b * NPB + blk];
    const int chunk = (E + NPB - 1) / NPB;
    const int beg = blk * chunk, end = min(beg + chunk, E);
    __syncthreads();
    for (int i = beg + tid; i < end; i += 256) {
        int d = dst[i];
        int b = d >> BSH;
        int pos = atomicAdd(&cur[b], 1);
        ebuf[pos] = ((unsigned)(d & (BNODES - 1)) << 16) | (unsigned)src[i];
    }
}

// ---- p4: per-bucket sort -> csr, rowptr, dis ----
__global__ __launch_bounds__(256) void p4_sort_kernel(
    const unsigned* __restrict__ ebuf, const int* __restrict__ totals,
    unsigned short* __restrict__ csr, int* __restrict__ rowptr,
    float* __restrict__ dis, int N, int E, int nbuck)
{
    __shared__ int counts[BNODES];
    __shared__ int cursor[BNODES];
    __shared__ int sbase[MAXBUCK];
    __shared__ int wsum[4];
    __shared__ int w2[2];
    __shared__ unsigned short staging[P4CAP];
    const int b = blockIdx.x, tid = threadIdx.x, lane = tid & 63, wid = tid >> 6;

    scan_totals2(totals, sbase, wsum, nbuck, tid);
    __syncthreads();
    const int gbase = sbase[b];
    const int cnt = totals[b];

    if (tid < BNODES) counts[tid] = 0;
    __syncthreads();
    for (int i = tid; i < cnt; i += 256)
        atomicAdd(&counts[ebuf[gbase + i] >> 16], 1);
    __syncthreads();

    // exclusive scan of BNODES=128 counts (first 2 waves)
    int c = 0, s = 0;
    if (tid < BNODES) {
        c = counts[tid];
        s = c;
#pragma unroll
        for (int off = 1; off < 64; off <<= 1) {
            int t = __shfl_up(s, off, 64);
            if (lane >= off) s += t;
        }
        if (lane == 63) w2[wid] = s;
    }
    __syncthreads();
    if (tid == 0) { int t = w2[0]; w2[0] = 0; w2[1] = t; }
    __syncthreads();
    if (tid < BNODES) {
        int excl = w2[wid] + s - c;
        cursor[tid] = excl;
        int node = b * BNODES + tid;
        if (node < N) {
            rowptr[node] = gbase + excl;
            dis[node] = rsqrtf(1.0f + (float)c);
        }
    }
    if (b == 0 && tid == 0) rowptr[N] = E;
    __syncthreads();

    if (cnt <= P4CAP) {
        for (int i = tid; i < cnt; i += 256) {
            unsigned v = ebuf[gbase + i];
            int pos = atomicAdd(&cursor[v >> 16], 1);
            staging[pos] = (unsigned short)(v & 0xFFFFu);
        }
        __syncthreads();
        for (int i = tid; i < cnt; i += 256)
            csr[gbase + i] = staging[i];
    } else {
        for (int i = tid; i < cnt; i += 256) {
            unsigned v = ebuf[gbase + i];
            int pos = atomicAdd(&cursor[v >> 16], 1);
            csr[gbase + pos] = (unsigned short)(v & 0xFFFFu);
        }
    }
}

// ---- xconv: Xhs = bf16(dis * X) [N][KP], zero-padded cols 89..127 ----
__global__ __launch_bounds__(256) void xconv_kernel(
    const float* __restrict__ X, const float* __restrict__ dis,
    unsigned* __restrict__ Xhs, int N)
{
    int t = blockIdx.x * 256 + threadIdx.x;
    if (t >= N * (KP / 2)) return;
    int n = t / (KP / 2), c = t % (KP / 2);
    float d = dis[n];
    const float* xr = X + (size_t)n * KIN;
    float a = (2 * c     < KIN) ? d * xr[2 * c]     : 0.0f;
    float b = (2 * c + 1 < KIN) ? d * xr[2 * c + 1] : 0.0f;
    Xhs[t] = pack_bf16(a, b);
}

// ---- gather: 4 nodes per wave, 16 lanes x uint4 = full 256B row per inst ----
// 4 independent csr->row dependency chains per wave (MLP), no cross-lane
// reduction. rows are [N][16] uint4 (256B bf16 rows).
__global__ __launch_bounds__(256) void gather_kernel(
    const uint4* __restrict__ rows, const int* __restrict__ rowptr,
    const unsigned short* __restrict__ csr, uint4* __restrict__ aggh, int N)
{
    const int lane = threadIdx.x & 63;
    const int sub  = lane >> 4;          // node slot within wave (0..3)
    const int sl   = lane & 15;          // 16B chunk within row
    const int node = (blockIdx.x * 4 + (threadIdx.x >> 6)) * 4 + sub;
    const bool valid = node < N;
    const int cn = valid ? node : N - 1;

    // self row (added once)
    uint4 sv = rows[(size_t)cn * 16 + sl];
    float a0, a1, a2, a3, a4, a5, a6, a7;
    {
        float2 p;
        p = unpack_bf16(sv.x); a0 = p.x; a1 = p.y;
        p = unpack_bf16(sv.y); a2 = p.x; a3 = p.y;
        p = unpack_bf16(sv.z); a4 = p.x; a5 = p.y;
        p = unpack_bf16(sv.w); a6 = p.x; a7 = p.y;
    }

    int beg = rowptr[cn];
    int end = valid ? rowptr[cn + 1] : beg;
    int j = beg;
    for (; j + 4 <= end; j += 4) {       // 4 rows in flight per chain
        int r0 = csr[j], r1 = csr[j + 1], r2 = csr[j + 2], r3 = csr[j + 3];
        uint4 v0 = rows[(size_t)r0 * 16 + sl];
        uint4 v1 = rows[(size_t)r1 * 16 + sl];
        uint4 v2 = rows[(size_t)r2 * 16 + sl];
        uint4 v3 = rows[(size_t)r3 * 16 + sl];
        float2 p;
        p = unpack_bf16(v0.x); a0 += p.x; a1 += p.y;
        p = unpack_bf16(v0.y); a2 += p.x; a3 += p.y;
        p = unpack_bf16(v0.z); a4 += p.x; a5 += p.y;
        p = unpack_bf16(v0.w); a6 += p.x; a7 += p.y;
        p = unpack_bf16(v1.x); a0 += p.x; a1 += p.y;
        p = unpack_bf16(v1.y); a2 += p.x; a3 += p.y;
        p = unpack_bf16(v1.z); a4 += p.x; a5 += p.y;
        p = unpack_bf16(v1.w); a6 += p.x; a7 += p.y;
        p = unpack_bf16(v2.x); a0 += p.x; a1 += p.y;
        p = unpack_bf16(v2.y); a2 += p.x; a3 += p.y;
        p = unpack_bf16(v2.z); a4 += p.x; a5 += p.y;
        p = unpack_bf16(v2.w); a6 += p.x; a7 += p.y;
        p = unpack_bf16(v3.x); a0 += p.x; a1 += p.y;
        p = unpack_bf16(v3.y); a2 += p.x; a3 += p.y;
        p = unpack_bf16(v3.z); a4 += p.x; a5 += p.y;
        p = unpack_bf16(v3.w); a6 += p.x; a7 += p.y;
    }
    for (; j < end; ++j) {
        int r = csr[j];
        uint4 v = rows[(size_t)r * 16 + sl];
        float2 p;
        p = unpack_bf16(v.x); a0 += p.x; a1 += p.y;
        p = unpack_bf16(v.y); a2 += p.x; a3 += p.y;
        p = unpack_bf16(v.z); a4 += p.x; a5 += p.y;
        p = unpack_bf16(v.w); a6 += p.x; a7 += p.y;
    }

    if (valid)
        aggh[(size_t)node * 16 + sl] =
            make_uint4(pack_bf16(a0, a1), pack_bf16(a2, a3),
                       pack_bf16(a4, a5), pack_bf16(a6, a7));
}

// ---- MFMA GEMM (no LDS, transposed-D epilogue) ----
// Block = 64 nodes (4 waves x 16), wave covers 128 cols as 8 16x16 tiles.
//   LAYER1: store bf16( relu(d*acc + b) * d )     (pre-scaled rows for layer 2)
//   LAYER2: store fp32( relu(d*acc + b) )
template<int KPA, bool LAYER1>
__global__ __launch_bounds__(256) void mfma_gemm_kernel(
    const unsigned short* __restrict__ A, const unsigned short* __restrict__ Wt,
    const float* __restrict__ bias, const float* __restrict__ dis,
    void* __restrict__ outp, int N)
{
    const int wave = threadIdx.x >> 6;
    const int lane = threadIdx.x & 63;
    const int m    = lane & 15;
    const int quad = lane >> 4;
    const int row0 = blockIdx.x * 64 + wave * 16;
    const int node = row0 + m;

    f32x4 acc[8];
#pragma unroll
    for (int t = 0; t < 8; ++t) acc[t] = (f32x4){0.0f, 0.0f, 0.0f, 0.0f};

    const int arow = min(node, N - 1);           // clamp: stores are guarded
    const unsigned short* arp = A + (size_t)arow * KPA;

#pragma unroll
    for (int c = 0; c < KPA / 32; ++c) {
        const int k0 = c * 32 + quad * 8;
        bf16x8 nv = *(const bf16x8*)(arp + k0);                      // B-frag
#pragma unroll
        for (int t = 0; t < 8; ++t) {
            bf16x8 wv = *(const bf16x8*)(Wt + (size_t)(t * 16 + m) * KPA + k0);  // A-frag
            acc[t] = __builtin_amdgcn_mfma_f32_16x16x32_bf16(wv, nv, acc[t], 0, 0, 0);
        }
    }

    if (node < N) {
        const float dv = dis[node];
#pragma unroll
        for (int t = 0; t < 8; ++t) {
            const int col0 = t * 16 + quad * 4;
            float4 bb = *(const float4*)&bias[col0];
            float r0 = fmaxf(fmaf(dv, acc[t][0], bb.x), 0.0f);
            float r1 = fmaxf(fmaf(dv, acc[t][1], bb.y), 0.0f);
            float r2 = fmaxf(fmaf(dv, acc[t][2], bb.z), 0.0f);
            float r3 = fmaxf(fmaf(dv, acc[t][3], bb.w), 0.0f);
            if (LAYER1) {
                uint2 u;
                u.x = pack_bf16(r0 * dv, r1 * dv);
                u.y = pack_bf16(r2 * dv, r3 * dv);
                *(uint2*)((unsigned short*)outp + (size_t)node * HID + col0) = u;
            } else {
                float4 r = make_float4(r0, r1, r2, r3);
                *(float4*)((float*)outp + (size_t)node * HID + col0) = r;
            }
        }
    }
}

// ---------------- launch ----------------

static inline char* wsal(char*& p, size_t n) {
    uintptr_t q = ((uintptr_t)p + 255) & ~(uintptr_t)255;
    char* r = (char*)q;
    p = r + n;
    return r;
}

extern "C" void kernel_launch(void* const* d_in, const int* in_sizes, int n_in,
                              void* d_out, int out_size, void* d_ws, size_t ws_size,
                              hipStream_t stream) {
    const float* x  = (const float*)d_in[0];
    const int*   ei = (const int*)d_in[1];
    const float* W1 = (const float*)d_in[2];
    const float* b1 = (const float*)d_in[3];
    const float* W2 = (const float*)d_in[4];
    const float* b2 = (const float*)d_in[5];

    const int N = in_sizes[0] / KIN;  // 50000  (< 65536 required)
    const int E = in_sizes[1] / 2;    // 800000
    const int nbuck = (N + BNODES - 1) >> BSH;   // 391 (<= MAXBUCK)

    float* out  = (float*)d_out;
    float* outH = out;                      // [N,128] final fp32 output
    float* outE = out + (size_t)N * HID;    // [2,E] edge_index as float

    char* ws = (char*)d_ws;
    int*            histG  = (int*)wsal(ws, (size_t)MAXBUCK * NPB * 4);
    int*            totals = (int*)wsal(ws, MAXBUCK * 4);
    int*            rowptr = (int*)wsal(ws, (size_t)(N + 1) * 4);
    float*          dis    = (float*)wsal(ws, (size_t)N * 4);
    unsigned*       ebuf   = (unsigned*)wsal(ws, (size_t)E * 4);
    unsigned short* csr    = (unsigned short*)wsal(ws, (size_t)E * 2);
    unsigned*       Xhs    = (unsigned*)wsal(ws, (size_t)N * (KP / 2) * 4);
    unsigned*       agg1h  = (unsigned*)wsal(ws, (size_t)N * (KP / 2) * 4);
    unsigned short* g2h    = (unsigned short*)wsal(ws, (size_t)N * HID * 2);
    unsigned short* agg2h  = (unsigned short*)wsal(ws, (size_t)N * HID * 2);
    unsigned short* W1t    = (unsigned short*)wsal(ws, (size_t)HID * KP * 2);
    unsigned short* W2t    = (unsigned short*)wsal(ws, (size_t)HID * HID * 2);

    p1_kernel<<<NPB, 256, 0, stream>>>(ei, outE, histG, W1, W1t, W2, W2t, E, nbuck);
    p2a_kernel<<<nbuck, NPB, 0, stream>>>(histG, totals);
    p3_part_kernel<<<NPB, 256, 0, stream>>>(ei, histG, totals, ebuf, E, nbuck);
    p4_sort_kernel<<<nbuck, 256, 0, stream>>>(ebuf, totals, csr, rowptr, dis,
                                              N, E, nbuck);
    xconv_kernel<<<(N * (KP / 2) + 255) / 256, 256, 0, stream>>>(x, dis, Xhs, N);

    const int ngt = (N + 15) / 16;   // 16 nodes per 256-thread block
    const int ngm = (N + 63) / 64;

    // Layer 1
    gather_kernel<<<ngt, 256, 0, stream>>>((const uint4*)Xhs, rowptr, csr,
                                           (uint4*)agg1h, N);
    mfma_gemm_kernel<KP, true><<<ngm, 256, 0, stream>>>(
        (const unsigned short*)agg1h, W1t, b1, dis, g2h, N);

    // Layer 2
    gather_kernel<<<ngt, 256, 0, stream>>>((const uint4*)g2h, rowptr, csr,
                                           (uint4*)agg2h, N);
    mfma_gemm_kernel<HID, false><<<ngm, 256, 0, stream>>>(
        agg2h, W2t, b2, dis, outH, N);
}

// Round 6
// 220.655 us; speedup vs baseline: 2.0167x; 1.0274x over previous
//
#include <hip/hip_runtime.h>
#include <hip/hip_bf16.h>

// GCN 2-layer, 7 launches. Buckets of 128 nodes (391 buckets).
//   p1    : bucket histogram + edge_index copy-out + W1/W2 transpose->bf16
//   p2a   : scan of per-partition bucket counts
//   p3    : partition edges into bucket-contiguous ebuf
//   p4    : per-bucket counting sort -> csr(ushort), rowptr, dis
//   xconv : Xhs = bf16(dis*X) [N][128] (zero-padded 89->128)
//   fused1: per 64-node block: gather rows -> LDS, then MFMA GEMM
//           g2h = bf16( relu(d*(agg@W1t) + b1) * d )
//   fused2: same structure, out = relu( d*(agg@W2t) + b2 ) fp32
// All row operands bf16 (fp32 accumulation). Requires N < 65536.

#define HID 128
#define KIN 89
#define KP 128    // padded input dim (unified 256B rows, same as HID)
#define BSH 7     // bucket = 128 nodes
#define BNODES 128
#define MAXBUCK 512   // capacity of bucket-indexed LDS/scan arrays
#define NPB 128       // partition blocks
#define P4CAP 3072    // staging capacity per bucket (mean ~2046, 5sd ~2270)
#define LDSPAD 136    // 64-node LDS row stride in ushorts (272B: r*17%32 perm)

typedef __attribute__((ext_vector_type(8))) short bf16x8;
typedef __attribute__((ext_vector_type(4))) float f32x4;

static __device__ inline float2 unpack_bf16(unsigned v) {
    union { unsigned u; float f; } lo, hi;
    lo.u = v << 16;
    hi.u = v & 0xFFFF0000u;
    return make_float2(lo.f, hi.f);
}

static __device__ inline unsigned pack_bf16(float a, float b) {
    __hip_bfloat162 h = __float22bfloat162_rn(make_float2(a, b));
    return *reinterpret_cast<unsigned*>(&h);
}

static __device__ inline unsigned short f2bf(float v) {
    __hip_bfloat16 h = __float2bfloat16(v);
    return *reinterpret_cast<unsigned short*>(&h);
}

// ---- p1: histogram + edge copy + weight transposes ----
__global__ __launch_bounds__(256) void p1_kernel(
    const int* __restrict__ ei, float* __restrict__ outE,
    int* __restrict__ histG,
    const float* __restrict__ W1, unsigned short* __restrict__ W1t,
    const float* __restrict__ W2, unsigned short* __restrict__ W2t,
    int E, int nbuck)
{
    __shared__ int h[MAXBUCK];
    const int tid = threadIdx.x, blk = blockIdx.x;
    const int* src = ei;
    const int* dst = ei + E;
    for (int b = tid; b < nbuck; b += 256) h[b] = 0;

    // weight transposes spread over the grid's first 32768 threads
    int tg = blk * 256 + tid;
    if (tg < HID * KP) {
        int n = tg / KP, k = tg % KP;
        W1t[tg] = f2bf(k < KIN ? W1[(size_t)k * HID + n] : 0.0f);
    } else {
        int t2 = tg - HID * KP;
        if (t2 < HID * HID) {
            int n = t2 / HID, k = t2 % HID;
            W2t[t2] = f2bf(W2[(size_t)k * HID + n]);
        }
    }
    __syncthreads();

    const int chunk = (E + NPB - 1) / NPB;
    const int beg = blk * chunk, end = min(beg + chunk, E);
    for (int i = beg + tid; i < end; i += 256) {
        int d = dst[i];
        atomicAdd(&h[d >> BSH], 1);
        outE[i] = (float)src[i];
        outE[E + i] = (float)d;
    }
    __syncthreads();
    for (int b = tid; b < nbuck; b += 256) histG[b * NPB + blk] = h[b];
}

// ---- p2a: per-bucket exclusive scan of its NPB counts + totals ----
__global__ __launch_bounds__(NPB) void p2a_kernel(
    int* __restrict__ histG, int* __restrict__ totals)
{
    __shared__ int wsum[NPB / 64];
    const int b = blockIdx.x, tid = threadIdx.x, lane = tid & 63, wid = tid >> 6;
    int c = histG[b * NPB + tid];
    int s = c;
#pragma unroll
    for (int off = 1; off < 64; off <<= 1) {
        int t = __shfl_up(s, off, 64);
        if (lane >= off) s += t;
    }
    if (lane == 63) wsum[wid] = s;
    __syncthreads();
    if (tid == 0) {
        int a = 0;
#pragma unroll
        for (int w = 0; w < NPB / 64; ++w) { int t = wsum[w]; wsum[w] = a; a += t; }
    }
    __syncthreads();
    int excl = wsum[wid] + s - c;
    histG[b * NPB + tid] = excl;
    if (tid == NPB - 1) totals[b] = excl + c;
}

// In-block exclusive scan of totals[0..nbuck), nbuck <= 512, 256 threads.
static __device__ inline void scan_totals2(const int* __restrict__ totals,
                                           int* __restrict__ sexcl,
                                           int* __restrict__ wsum,
                                           int nbuck, int tid)
{
    const int lane = tid & 63, wid = tid >> 6;
    const int i0 = 2 * tid, i1 = 2 * tid + 1;
    int t0 = (i0 < nbuck) ? totals[i0] : 0;
    int t1 = (i1 < nbuck) ? totals[i1] : 0;
    int p = t0 + t1;
    int s = p;
#pragma unroll
    for (int off = 1; off < 64; off <<= 1) {
        int t = __shfl_up(s, off, 64);
        if (lane >= off) s += t;
    }
    if (lane == 63) wsum[wid] = s;
    __syncthreads();
    if (tid == 0) {
        int a = 0;
#pragma unroll
        for (int w = 0; w < 4; ++w) { int t = wsum[w]; wsum[w] = a; a += t; }
    }
    __syncthreads();
    int excl = wsum[wid] + s - p;
    sexcl[i0] = excl;
    sexcl[i1] = excl + t0;
}

// ---- p3: partition edges into bucket-contiguous ebuf ----
__global__ __launch_bounds__(256) void p3_part_kernel(
    const int* __restrict__ ei, const int* __restrict__ histG,
    const int* __restrict__ totals, unsigned* __restrict__ ebuf,
    int E, int nbuck)
{
    __shared__ int cur[MAXBUCK];
    __shared__ int wsum[4];
    const int tid = threadIdx.x, blk = blockIdx.x;
    const int* src = ei;
    const int* dst = ei + E;
    scan_totals2(totals, cur, wsum, nbuck, tid);   // cur[b] = bucket base
    __syncthreads();
    for (int b = tid; b < nbuck; b += 256) cur[b] += histG[b * NPB + blk];
    const int chunk = (E + NPB - 1) / NPB;
    const int beg = blk * chunk, end = min(beg + chunk, E);
    __syncthreads();
    for (int i = beg + tid; i < end; i += 256) {
        int d = dst[i];
        int b = d >> BSH;
        int pos = atomicAdd(&cur[b], 1);
        ebuf[pos] = ((unsigned)(d & (BNODES - 1)) << 16) | (unsigned)src[i];
    }
}

// ---- p4: per-bucket sort -> csr, rowptr, dis ----
__global__ __launch_bounds__(256) void p4_sort_kernel(
    const unsigned* __restrict__ ebuf, const int* __restrict__ totals,
    unsigned short* __restrict__ csr, int* __restrict__ rowptr,
    float* __restrict__ dis, int N, int E, int nbuck)
{
    __shared__ int counts[BNODES];
    __shared__ int cursor[BNODES];
    __shared__ int sbase[MAXBUCK];
    __shared__ int wsum[4];
    __shared__ int w2[2];
    __shared__ unsigned short staging[P4CAP];
    const int b = blockIdx.x, tid = threadIdx.x, lane = tid & 63, wid = tid >> 6;

    scan_totals2(totals, sbase, wsum, nbuck, tid);
    __syncthreads();
    const int gbase = sbase[b];
    const int cnt = totals[b];

    if (tid < BNODES) counts[tid] = 0;
    __syncthreads();
    for (int i = tid; i < cnt; i += 256)
        atomicAdd(&counts[ebuf[gbase + i] >> 16], 1);
    __syncthreads();

    // exclusive scan of BNODES=128 counts (first 2 waves)
    int c = 0, s = 0;
    if (tid < BNODES) {
        c = counts[tid];
        s = c;
#pragma unroll
        for (int off = 1; off < 64; off <<= 1) {
            int t = __shfl_up(s, off, 64);
            if (lane >= off) s += t;
        }
        if (lane == 63) w2[wid] = s;
    }
    __syncthreads();
    if (tid == 0) { int t = w2[0]; w2[0] = 0; w2[1] = t; }
    __syncthreads();
    if (tid < BNODES) {
        int excl = w2[wid] + s - c;
        cursor[tid] = excl;
        int node = b * BNODES + tid;
        if (node < N) {
            rowptr[node] = gbase + excl;
            dis[node] = rsqrtf(1.0f + (float)c);
        }
    }
    if (b == 0 && tid == 0) rowptr[N] = E;
    __syncthreads();

    if (cnt <= P4CAP) {
        for (int i = tid; i < cnt; i += 256) {
            unsigned v = ebuf[gbase + i];
            int pos = atomicAdd(&cursor[v >> 16], 1);
            staging[pos] = (unsigned short)(v & 0xFFFFu);
        }
        __syncthreads();
        for (int i = tid; i < cnt; i += 256)
            csr[gbase + i] = staging[i];
    } else {
        for (int i = tid; i < cnt; i += 256) {
            unsigned v = ebuf[gbase + i];
            int pos = atomicAdd(&cursor[v >> 16], 1);
            csr[gbase + pos] = (unsigned short)(v & 0xFFFFu);
        }
    }
}

// ---- xconv: Xhs = bf16(dis * X) [N][KP], zero-padded cols 89..127 ----
__global__ __launch_bounds__(256) void xconv_kernel(
    const float* __restrict__ X, const float* __restrict__ dis,
    unsigned* __restrict__ Xhs, int N)
{
    int t = blockIdx.x * 256 + threadIdx.x;
    if (t >= N * (KP / 2)) return;
    int n = t / (KP / 2), c = t % (KP / 2);
    float d = dis[n];
    const float* xr = X + (size_t)n * KIN;
    float a = (2 * c     < KIN) ? d * xr[2 * c]     : 0.0f;
    float b = (2 * c + 1 < KIN) ? d * xr[2 * c + 1] : 0.0f;
    Xhs[t] = pack_bf16(a, b);
}

// ---- fused: gather 64 nodes -> LDS (bf16), then MFMA GEMM from LDS ----
// Gather: 4 passes x (4 nodes/wave, 16 lanes x uint4 = full 256B row/inst),
// 4 independent csr->row chains per wave. LDS rows padded to 136 ushorts
// (272B) so the GEMM's 16 m-lanes map to distinct banks (r*17 mod 32 perm).
// GEMM: block = 64 nodes (4 waves x 16), wave covers 128 cols as 8 16x16
// tiles; B-frag (node row) from LDS, A-frag (weights) from global.
//   LAYER1: store bf16( relu(d*acc + b) * d )   (pre-scaled rows for layer 2)
//   LAYER2: store fp32( relu(d*acc + b) )
template<bool LAYER1>
__global__ __launch_bounds__(256) void fused_kernel(
    const uint4* __restrict__ rows, const int* __restrict__ rowptr,
    const unsigned short* __restrict__ csr,
    const unsigned short* __restrict__ Wt, const float* __restrict__ bias,
    const float* __restrict__ dis, void* __restrict__ outp, int N)
{
    __shared__ unsigned short lds_a[64][LDSPAD];
    const int tid  = threadIdx.x;
    const int wave = tid >> 6;
    const int lane = tid & 63;
    const int sub  = (lane >> 4) & 3;    // node slot within wave (0..3)
    const int sl   = lane & 15;          // 16B chunk within row
    const int blk0 = blockIdx.x * 64;

    // ---- gather phase: 4 passes, wave w fills LDS rows w*16 .. w*16+15 ----
#pragma unroll
    for (int p = 0; p < 4; ++p) {
        const int lrow = wave * 16 + p * 4 + sub;
        const int node = blk0 + lrow;
        const bool valid = node < N;
        const int cn = valid ? node : N - 1;

        // self row (added once)
        uint4 sv = rows[(size_t)cn * 16 + sl];
        float a0, a1, a2, a3, a4, a5, a6, a7;
        {
            float2 q;
            q = unpack_bf16(sv.x); a0 = q.x; a1 = q.y;
            q = unpack_bf16(sv.y); a2 = q.x; a3 = q.y;
            q = unpack_bf16(sv.z); a4 = q.x; a5 = q.y;
            q = unpack_bf16(sv.w); a6 = q.x; a7 = q.y;
        }

        int beg = rowptr[cn];
        int end = valid ? rowptr[cn + 1] : beg;
        int j = beg;
        for (; j + 4 <= end; j += 4) {   // 4 rows in flight per chain
            int r0 = csr[j], r1 = csr[j + 1], r2 = csr[j + 2], r3 = csr[j + 3];
            uint4 v0 = rows[(size_t)r0 * 16 + sl];
            uint4 v1 = rows[(size_t)r1 * 16 + sl];
            uint4 v2 = rows[(size_t)r2 * 16 + sl];
            uint4 v3 = rows[(size_t)r3 * 16 + sl];
            float2 q;
            q = unpack_bf16(v0.x); a0 += q.x; a1 += q.y;
            q = unpack_bf16(v0.y); a2 += q.x; a3 += q.y;
            q = unpack_bf16(v0.z); a4 += q.x; a5 += q.y;
            q = unpack_bf16(v0.w); a6 += q.x; a7 += q.y;
            q = unpack_bf16(v1.x); a0 += q.x; a1 += q.y;
            q = unpack_bf16(v1.y); a2 += q.x; a3 += q.y;
            q = unpack_bf16(v1.z); a4 += q.x; a5 += q.y;
            q = unpack_bf16(v1.w); a6 += q.x; a7 += q.y;
            q = unpack_bf16(v2.x); a0 += q.x; a1 += q.y;
            q = unpack_bf16(v2.y); a2 += q.x; a3 += q.y;
            q = unpack_bf16(v2.z); a4 += q.x; a5 += q.y;
            q = unpack_bf16(v2.w); a6 += q.x; a7 += q.y;
            q = unpack_bf16(v3.x); a0 += q.x; a1 += q.y;
            q = unpack_bf16(v3.y); a2 += q.x; a3 += q.y;
            q = unpack_bf16(v3.z); a4 += q.x; a5 += q.y;
            q = unpack_bf16(v3.w); a6 += q.x; a7 += q.y;
        }
        for (; j < end; ++j) {
            int r = csr[j];
            uint4 v = rows[(size_t)r * 16 + sl];
            float2 q;
            q = unpack_bf16(v.x); a0 += q.x; a1 += q.y;
            q = unpack_bf16(v.y); a2 += q.x; a3 += q.y;
            q = unpack_bf16(v.z); a4 += q.x; a5 += q.y;
            q = unpack_bf16(v.w); a6 += q.x; a7 += q.y;
        }

        uint4 pk = make_uint4(pack_bf16(a0, a1), pack_bf16(a2, a3),
                              pack_bf16(a4, a5), pack_bf16(a6, a7));
        *(uint4*)&lds_a[lrow][sl * 8] = pk;
    }
    __syncthreads();

    // ---- gemm phase ----
    const int m    = lane & 15;
    const int quad = lane >> 4;
    const int node = blk0 + wave * 16 + m;

    f32x4 acc[8];
#pragma unroll
    for (int t = 0; t < 8; ++t) acc[t] = (f32x4){0.0f, 0.0f, 0.0f, 0.0f};

    const unsigned short* arp = &lds_a[wave * 16 + m][0];

#pragma unroll
    for (int c = 0; c < KP / 32; ++c) {
        const int k0 = c * 32 + quad * 8;
        bf16x8 nv = *(const bf16x8*)(arp + k0);                      // B-frag (LDS)
#pragma unroll
        for (int t = 0; t < 8; ++t) {
            bf16x8 wv = *(const bf16x8*)(Wt + (size_t)(t * 16 + m) * KP + k0);  // A-frag
            acc[t] = __builtin_amdgcn_mfma_f32_16x16x32_bf16(wv, nv, acc[t], 0, 0, 0);
        }
    }

    if (node < N) {
        const float dv = dis[node];
#pragma unroll
        for (int t = 0; t < 8; ++t) {
            const int col0 = t * 16 + quad * 4;
            float4 bb = *(const float4*)&bias[col0];
            float r0 = fmaxf(fmaf(dv, acc[t][0], bb.x), 0.0f);
            float r1 = fmaxf(fmaf(dv, acc[t][1], bb.y), 0.0f);
            float r2 = fmaxf(fmaf(dv, acc[t][2], bb.z), 0.0f);
            float r3 = fmaxf(fmaf(dv, acc[t][3], bb.w), 0.0f);
            if (LAYER1) {
                uint2 u;
                u.x = pack_bf16(r0 * dv, r1 * dv);
                u.y = pack_bf16(r2 * dv, r3 * dv);
                *(uint2*)((unsigned short*)outp + (size_t)node * HID + col0) = u;
            } else {
                float4 r = make_float4(r0, r1, r2, r3);
                *(float4*)((float*)outp + (size_t)node * HID + col0) = r;
            }
        }
    }
}

// ---------------- launch ----------------

static inline char* wsal(char*& p, size_t n) {
    uintptr_t q = ((uintptr_t)p + 255) & ~(uintptr_t)255;
    char* r = (char*)q;
    p = r + n;
    return r;
}

extern "C" void kernel_launch(void* const* d_in, const int* in_sizes, int n_in,
                              void* d_out, int out_size, void* d_ws, size_t ws_size,
                              hipStream_t stream) {
    const float* x  = (const float*)d_in[0];
    const int*   ei = (const int*)d_in[1];
    const float* W1 = (const float*)d_in[2];
    const float* b1 = (const float*)d_in[3];
    const float* W2 = (const float*)d_in[4];
    const float* b2 = (const float*)d_in[5];

    const int N = in_sizes[0] / KIN;  // 50000  (< 65536 required)
    const int E = in_sizes[1] / 2;    // 800000
    const int nbuck = (N + BNODES - 1) >> BSH;   // 391 (<= MAXBUCK)

    float* out  = (float*)d_out;
    float* outH = out;                      // [N,128] final fp32 output
    float* outE = out + (size_t)N * HID;    // [2,E] edge_index as float

    char* ws = (char*)d_ws;
    int*            histG  = (int*)wsal(ws, (size_t)MAXBUCK * NPB * 4);
    int*            totals = (int*)wsal(ws, MAXBUCK * 4);
    int*            rowptr = (int*)wsal(ws, (size_t)(N + 1) * 4);
    float*          dis    = (float*)wsal(ws, (size_t)N * 4);
    unsigned*       ebuf   = (unsigned*)wsal(ws, (size_t)E * 4);
    unsigned short* csr    = (unsigned short*)wsal(ws, (size_t)E * 2);
    unsigned*       Xhs    = (unsigned*)wsal(ws, (size_t)N * (KP / 2) * 4);
    unsigned short* g2h    = (unsigned short*)wsal(ws, (size_t)N * HID * 2);
    unsigned short* W1t    = (unsigned short*)wsal(ws, (size_t)HID * KP * 2);
    unsigned short* W2t    = (unsigned short*)wsal(ws, (size_t)HID * HID * 2);

    p1_kernel<<<NPB, 256, 0, stream>>>(ei, outE, histG, W1, W1t, W2, W2t, E, nbuck);
    p2a_kernel<<<nbuck, NPB, 0, stream>>>(histG, totals);
    p3_part_kernel<<<NPB, 256, 0, stream>>>(ei, histG, totals, ebuf, E, nbuck);
    p4_sort_kernel<<<nbuck, 256, 0, stream>>>(ebuf, totals, csr, rowptr, dis,
                                              N, E, nbuck);
    xconv_kernel<<<(N * (KP / 2) + 255) / 256, 256, 0, stream>>>(x, dis, Xhs, N);

    const int ngf = (N + 63) / 64;

    // Layer 1: fused gather+gemm  (Xhs -> g2h)
    fused_kernel<true><<<ngf, 256, 0, stream>>>(
        (const uint4*)Xhs, rowptr, csr, W1t, b1, dis, g2h, N);

    // Layer 2: fused gather+gemm  (g2h -> outH)
    fused_kernel<false><<<ngf, 256, 0, stream>>>(
        (const uint4*)g2h, rowptr, csr, W2t, b2, dis, outH, N);
}

// Round 7
// 203.844 us; speedup vs baseline: 2.1831x; 1.0825x over previous
//
#include <hip/hip_runtime.h>
#include <hip/hip_bf16.h>

// GCN 2-layer, 7 launches. Buckets of 128 nodes (391 buckets).
//   p1    : bucket histogram + edge_index copy-out + W1/W2 transpose->bf16
//   p2a   : scan of per-partition bucket counts
//   p3    : partition edges into bucket-contiguous ebuf
//   p4    : per-bucket counting sort -> csr(ushort), rowptr, dis
//   xconv : Xhs = bf16(dis*X) [N][128] (zero-padded 89->128)
//   fused1: per 16-node block: gather rows -> LDS, then MFMA GEMM
//           g2h = bf16( relu(d*(agg@W1t) + b1) * d )
//   fused2: same structure, out = relu( d*(agg@W2t) + b2 ) fp32
// 16 nodes/block (grid N/16=3125) => ~32 waves/CU during gather (vs 12 at
// 64 nodes/block, which profiled latency-bound at Occupancy 25%).
// All row operands bf16 (fp32 accumulation). Requires N < 65536.

#define HID 128
#define KIN 89
#define KP 128    // padded input dim (unified 256B rows, same as HID)
#define BSH 7     // bucket = 128 nodes
#define BNODES 128
#define MAXBUCK 512   // capacity of bucket-indexed LDS/scan arrays
#define NPB 128       // partition blocks
#define P4CAP 3072    // staging capacity per bucket (mean ~2046, 5sd ~2270)
#define LDSPAD 136    // LDS row stride in ushorts (272B; 2-way bank alias max)

typedef __attribute__((ext_vector_type(8))) short bf16x8;
typedef __attribute__((ext_vector_type(4))) float f32x4;

static __device__ inline float2 unpack_bf16(unsigned v) {
    union { unsigned u; float f; } lo, hi;
    lo.u = v << 16;
    hi.u = v & 0xFFFF0000u;
    return make_float2(lo.f, hi.f);
}

static __device__ inline unsigned pack_bf16(float a, float b) {
    __hip_bfloat162 h = __float22bfloat162_rn(make_float2(a, b));
    return *reinterpret_cast<unsigned*>(&h);
}

static __device__ inline unsigned short f2bf(float v) {
    __hip_bfloat16 h = __float2bfloat16(v);
    return *reinterpret_cast<unsigned short*>(&h);
}

// ---- p1: histogram + edge copy + weight transposes ----
__global__ __launch_bounds__(256) void p1_kernel(
    const int* __restrict__ ei, float* __restrict__ outE,
    int* __restrict__ histG,
    const float* __restrict__ W1, unsigned short* __restrict__ W1t,
    const float* __restrict__ W2, unsigned short* __restrict__ W2t,
    int E, int nbuck)
{
    __shared__ int h[MAXBUCK];
    const int tid = threadIdx.x, blk = blockIdx.x;
    const int* src = ei;
    const int* dst = ei + E;
    for (int b = tid; b < nbuck; b += 256) h[b] = 0;

    // weight transposes spread over the grid's first 32768 threads
    int tg = blk * 256 + tid;
    if (tg < HID * KP) {
        int n = tg / KP, k = tg % KP;
        W1t[tg] = f2bf(k < KIN ? W1[(size_t)k * HID + n] : 0.0f);
    } else {
        int t2 = tg - HID * KP;
        if (t2 < HID * HID) {
            int n = t2 / HID, k = t2 % HID;
            W2t[t2] = f2bf(W2[(size_t)k * HID + n]);
        }
    }
    __syncthreads();

    const int chunk = (E + NPB - 1) / NPB;
    const int beg = blk * chunk, end = min(beg + chunk, E);
    for (int i = beg + tid; i < end; i += 256) {
        int d = dst[i];
        atomicAdd(&h[d >> BSH], 1);
        outE[i] = (float)src[i];
        outE[E + i] = (float)d;
    }
    __syncthreads();
    for (int b = tid; b < nbuck; b += 256) histG[b * NPB + blk] = h[b];
}

// ---- p2a: per-bucket exclusive scan of its NPB counts + totals ----
__global__ __launch_bounds__(NPB) void p2a_kernel(
    int* __restrict__ histG, int* __restrict__ totals)
{
    __shared__ int wsum[NPB / 64];
    const int b = blockIdx.x, tid = threadIdx.x, lane = tid & 63, wid = tid >> 6;
    int c = histG[b * NPB + tid];
    int s = c;
#pragma unroll
    for (int off = 1; off < 64; off <<= 1) {
        int t = __shfl_up(s, off, 64);
        if (lane >= off) s += t;
    }
    if (lane == 63) wsum[wid] = s;
    __syncthreads();
    if (tid == 0) {
        int a = 0;
#pragma unroll
        for (int w = 0; w < NPB / 64; ++w) { int t = wsum[w]; wsum[w] = a; a += t; }
    }
    __syncthreads();
    int excl = wsum[wid] + s - c;
    histG[b * NPB + tid] = excl;
    if (tid == NPB - 1) totals[b] = excl + c;
}

// In-block exclusive scan of totals[0..nbuck), nbuck <= 512, 256 threads.
static __device__ inline void scan_totals2(const int* __restrict__ totals,
                                           int* __restrict__ sexcl,
                                           int* __restrict__ wsum,
                                           int nbuck, int tid)
{
    const int lane = tid & 63, wid = tid >> 6;
    const int i0 = 2 * tid, i1 = 2 * tid + 1;
    int t0 = (i0 < nbuck) ? totals[i0] : 0;
    int t1 = (i1 < nbuck) ? totals[i1] : 0;
    int p = t0 + t1;
    int s = p;
#pragma unroll
    for (int off = 1; off < 64; off <<= 1) {
        int t = __shfl_up(s, off, 64);
        if (lane >= off) s += t;
    }
    if (lane == 63) wsum[wid] = s;
    __syncthreads();
    if (tid == 0) {
        int a = 0;
#pragma unroll
        for (int w = 0; w < 4; ++w) { int t = wsum[w]; wsum[w] = a; a += t; }
    }
    __syncthreads();
    int excl = wsum[wid] + s - p;
    sexcl[i0] = excl;
    sexcl[i1] = excl + t0;
}

// ---- p3: partition edges into bucket-contiguous ebuf ----
__global__ __launch_bounds__(256) void p3_part_kernel(
    const int* __restrict__ ei, const int* __restrict__ histG,
    const int* __restrict__ totals, unsigned* __restrict__ ebuf,
    int E, int nbuck)
{
    __shared__ int cur[MAXBUCK];
    __shared__ int wsum[4];
    const int tid = threadIdx.x, blk = blockIdx.x;
    const int* src = ei;
    const int* dst = ei + E;
    scan_totals2(totals, cur, wsum, nbuck, tid);   // cur[b] = bucket base
    __syncthreads();
    for (int b = tid; b < nbuck; b += 256) cur[b] += histG[b * NPB + blk];
    const int chunk = (E + NPB - 1) / NPB;
    const int beg = blk * chunk, end = min(beg + chunk, E);
    __syncthreads();
    for (int i = beg + tid; i < end; i += 256) {
        int d = dst[i];
        int b = d >> BSH;
        int pos = atomicAdd(&cur[b], 1);
        ebuf[pos] = ((unsigned)(d & (BNODES - 1)) << 16) | (unsigned)src[i];
    }
}

// ---- p4: per-bucket sort -> csr, rowptr, dis ----
__global__ __launch_bounds__(256) void p4_sort_kernel(
    const unsigned* __restrict__ ebuf, const int* __restrict__ totals,
    unsigned short* __restrict__ csr, int* __restrict__ rowptr,
    float* __restrict__ dis, int N, int E, int nbuck)
{
    __shared__ int counts[BNODES];
    __shared__ int cursor[BNODES];
    __shared__ int sbase[MAXBUCK];
    __shared__ int wsum[4];
    __shared__ int w2[2];
    __shared__ unsigned short staging[P4CAP];
    const int b = blockIdx.x, tid = threadIdx.x, lane = tid & 63, wid = tid >> 6;

    scan_totals2(totals, sbase, wsum, nbuck, tid);
    __syncthreads();
    const int gbase = sbase[b];
    const int cnt = totals[b];

    if (tid < BNODES) counts[tid] = 0;
    __syncthreads();
    for (int i = tid; i < cnt; i += 256)
        atomicAdd(&counts[ebuf[gbase + i] >> 16], 1);
    __syncthreads();

    // exclusive scan of BNODES=128 counts (first 2 waves)
    int c = 0, s = 0;
    if (tid < BNODES) {
        c = counts[tid];
        s = c;
#pragma unroll
        for (int off = 1; off < 64; off <<= 1) {
            int t = __shfl_up(s, off, 64);
            if (lane >= off) s += t;
        }
        if (lane == 63) w2[wid] = s;
    }
    __syncthreads();
    if (tid == 0) { int t = w2[0]; w2[0] = 0; w2[1] = t; }
    __syncthreads();
    if (tid < BNODES) {
        int excl = w2[wid] + s - c;
        cursor[tid] = excl;
        int node = b * BNODES + tid;
        if (node < N) {
            rowptr[node] = gbase + excl;
            dis[node] = rsqrtf(1.0f + (float)c);
        }
    }
    if (b == 0 && tid == 0) rowptr[N] = E;
    __syncthreads();

    if (cnt <= P4CAP) {
        for (int i = tid; i < cnt; i += 256) {
            unsigned v = ebuf[gbase + i];
            int pos = atomicAdd(&cursor[v >> 16], 1);
            staging[pos] = (unsigned short)(v & 0xFFFFu);
        }
        __syncthreads();
        for (int i = tid; i < cnt; i += 256)
            csr[gbase + i] = staging[i];
    } else {
        for (int i = tid; i < cnt; i += 256) {
            unsigned v = ebuf[gbase + i];
            int pos = atomicAdd(&cursor[v >> 16], 1);
            csr[gbase + pos] = (unsigned short)(v & 0xFFFFu);
        }
    }
}

// ---- xconv: Xhs = bf16(dis * X) [N][KP], zero-padded cols 89..127 ----
__global__ __launch_bounds__(256) void xconv_kernel(
    const float* __restrict__ X, const float* __restrict__ dis,
    unsigned* __restrict__ Xhs, int N)
{
    int t = blockIdx.x * 256 + threadIdx.x;
    if (t >= N * (KP / 2)) return;
    int n = t / (KP / 2), c = t % (KP / 2);
    float d = dis[n];
    const float* xr = X + (size_t)n * KIN;
    float a = (2 * c     < KIN) ? d * xr[2 * c]     : 0.0f;
    float b = (2 * c + 1 < KIN) ? d * xr[2 * c + 1] : 0.0f;
    Xhs[t] = pack_bf16(a, b);
}

// ---- fused: gather 16 nodes -> LDS (bf16), then MFMA GEMM from LDS ----
// Gather: one pass, 4 waves x 4 nodes/wave (16 lanes x uint4 = full 256B
// row per inst), 4 independent csr->row chains per wave.
// GEMM: 4 waves share the block's 16 rows (B-frag from LDS); wave w
// computes col tiles {2w, 2w+1} (A-frag = weights from global, L1/L2-hot).
//   LAYER1: store bf16( relu(d*acc + b) * d )   (pre-scaled rows for layer 2)
//   LAYER2: store fp32( relu(d*acc + b) )
template<bool LAYER1>
__global__ __launch_bounds__(256) void fused_kernel(
    const uint4* __restrict__ rows, const int* __restrict__ rowptr,
    const unsigned short* __restrict__ csr,
    const unsigned short* __restrict__ Wt, const float* __restrict__ bias,
    const float* __restrict__ dis, void* __restrict__ outp, int N)
{
    __shared__ unsigned short lds_a[16][LDSPAD];
    const int tid  = threadIdx.x;
    const int wave = tid >> 6;
    const int lane = tid & 63;
    const int sub  = (lane >> 4) & 3;    // node slot within wave (0..3)
    const int sl   = lane & 15;          // 16B chunk within row
    const int blk0 = blockIdx.x * 16;

    // ---- gather phase: wave w fills LDS rows w*4 .. w*4+3 ----
    {
        const int lrow = wave * 4 + sub;
        const int node = blk0 + lrow;
        const bool valid = node < N;
        const int cn = valid ? node : N - 1;

        // self row (added once)
        uint4 sv = rows[(size_t)cn * 16 + sl];
        float a0, a1, a2, a3, a4, a5, a6, a7;
        {
            float2 q;
            q = unpack_bf16(sv.x); a0 = q.x; a1 = q.y;
            q = unpack_bf16(sv.y); a2 = q.x; a3 = q.y;
            q = unpack_bf16(sv.z); a4 = q.x; a5 = q.y;
            q = unpack_bf16(sv.w); a6 = q.x; a7 = q.y;
        }

        int beg = rowptr[cn];
        int end = valid ? rowptr[cn + 1] : beg;
        int j = beg;
        for (; j + 4 <= end; j += 4) {   // 4 rows in flight per chain
            int r0 = csr[j], r1 = csr[j + 1], r2 = csr[j + 2], r3 = csr[j + 3];
            uint4 v0 = rows[(size_t)r0 * 16 + sl];
            uint4 v1 = rows[(size_t)r1 * 16 + sl];
            uint4 v2 = rows[(size_t)r2 * 16 + sl];
            uint4 v3 = rows[(size_t)r3 * 16 + sl];
            float2 q;
            q = unpack_bf16(v0.x); a0 += q.x; a1 += q.y;
            q = unpack_bf16(v0.y); a2 += q.x; a3 += q.y;
            q = unpack_bf16(v0.z); a4 += q.x; a5 += q.y;
            q = unpack_bf16(v0.w); a6 += q.x; a7 += q.y;
            q = unpack_bf16(v1.x); a0 += q.x; a1 += q.y;
            q = unpack_bf16(v1.y); a2 += q.x; a3 += q.y;
            q = unpack_bf16(v1.z); a4 += q.x; a5 += q.y;
            q = unpack_bf16(v1.w); a6 += q.x; a7 += q.y;
            q = unpack_bf16(v2.x); a0 += q.x; a1 += q.y;
            q = unpack_bf16(v2.y); a2 += q.x; a3 += q.y;
            q = unpack_bf16(v2.z); a4 += q.x; a5 += q.y;
            q = unpack_bf16(v2.w); a6 += q.x; a7 += q.y;
            q = unpack_bf16(v3.x); a0 += q.x; a1 += q.y;
            q = unpack_bf16(v3.y); a2 += q.x; a3 += q.y;
            q = unpack_bf16(v3.z); a4 += q.x; a5 += q.y;
            q = unpack_bf16(v3.w); a6 += q.x; a7 += q.y;
        }
        for (; j < end; ++j) {
            int r = csr[j];
            uint4 v = rows[(size_t)r * 16 + sl];
            float2 q;
            q = unpack_bf16(v.x); a0 += q.x; a1 += q.y;
            q = unpack_bf16(v.y); a2 += q.x; a3 += q.y;
            q = unpack_bf16(v.z); a4 += q.x; a5 += q.y;
            q = unpack_bf16(v.w); a6 += q.x; a7 += q.y;
        }

        uint4 pk = make_uint4(pack_bf16(a0, a1), pack_bf16(a2, a3),
                              pack_bf16(a4, a5), pack_bf16(a6, a7));
        *(uint4*)&lds_a[lrow][sl * 8] = pk;
    }
    __syncthreads();

    // ---- gemm phase: wave w -> col tiles {2w, 2w+1} over the 16 rows ----
    const int m    = lane & 15;
    const int quad = lane >> 4;
    const int node = blk0 + m;

    f32x4 acc[2];
    acc[0] = (f32x4){0.0f, 0.0f, 0.0f, 0.0f};
    acc[1] = (f32x4){0.0f, 0.0f, 0.0f, 0.0f};

    const unsigned short* arp = &lds_a[m][0];

#pragma unroll
    for (int c = 0; c < KP / 32; ++c) {
        const int k0 = c * 32 + quad * 8;
        bf16x8 nv = *(const bf16x8*)(arp + k0);                      // B-frag (LDS)
#pragma unroll
        for (int t2 = 0; t2 < 2; ++t2) {
            const int t = wave * 2 + t2;
            bf16x8 wv = *(const bf16x8*)(Wt + (size_t)(t * 16 + m) * KP + k0);  // A-frag
            acc[t2] = __builtin_amdgcn_mfma_f32_16x16x32_bf16(wv, nv, acc[t2], 0, 0, 0);
        }
    }

    if (node < N) {
        const float dv = dis[node];
#pragma unroll
        for (int t2 = 0; t2 < 2; ++t2) {
            const int col0 = (wave * 2 + t2) * 16 + quad * 4;
            float4 bb = *(const float4*)&bias[col0];
            float r0 = fmaxf(fmaf(dv, acc[t2][0], bb.x), 0.0f);
            float r1 = fmaxf(fmaf(dv, acc[t2][1], bb.y), 0.0f);
            float r2 = fmaxf(fmaf(dv, acc[t2][2], bb.z), 0.0f);
            float r3 = fmaxf(fmaf(dv, acc[t2][3], bb.w), 0.0f);
            if (LAYER1) {
                uint2 u;
                u.x = pack_bf16(r0 * dv, r1 * dv);
                u.y = pack_bf16(r2 * dv, r3 * dv);
                *(uint2*)((unsigned short*)outp + (size_t)node * HID + col0) = u;
            } else {
                float4 r = make_float4(r0, r1, r2, r3);
                *(float4*)((float*)outp + (size_t)node * HID + col0) = r;
            }
        }
    }
}

// ---------------- launch ----------------

static inline char* wsal(char*& p, size_t n) {
    uintptr_t q = ((uintptr_t)p + 255) & ~(uintptr_t)255;
    char* r = (char*)q;
    p = r + n;
    return r;
}

extern "C" void kernel_launch(void* const* d_in, const int* in_sizes, int n_in,
                              void* d_out, int out_size, void* d_ws, size_t ws_size,
                              hipStream_t stream) {
    const float* x  = (const float*)d_in[0];
    const int*   ei = (const int*)d_in[1];
    const float* W1 = (const float*)d_in[2];
    const float* b1 = (const float*)d_in[3];
    const float* W2 = (const float*)d_in[4];
    const float* b2 = (const float*)d_in[5];

    const int N = in_sizes[0] / KIN;  // 50000  (< 65536 required)
    const int E = in_sizes[1] / 2;    // 800000
    const int nbuck = (N + BNODES - 1) >> BSH;   // 391 (<= MAXBUCK)

    float* out  = (float*)d_out;
    float* outH = out;                      // [N,128] final fp32 output
    float* outE = out + (size_t)N * HID;    // [2,E] edge_index as float

    char* ws = (char*)d_ws;
    int*            histG  = (int*)wsal(ws, (size_t)MAXBUCK * NPB * 4);
    int*            totals = (int*)wsal(ws, MAXBUCK * 4);
    int*            rowptr = (int*)wsal(ws, (size_t)(N + 1) * 4);
    float*          dis    = (float*)wsal(ws, (size_t)N * 4);
    unsigned*       ebuf   = (unsigned*)wsal(ws, (size_t)E * 4);
    unsigned short* csr    = (unsigned short*)wsal(ws, (size_t)E * 2);
    unsigned*       Xhs    = (unsigned*)wsal(ws, (size_t)N * (KP / 2) * 4);
    unsigned short* g2h    = (unsigned short*)wsal(ws, (size_t)N * HID * 2);
    unsigned short* W1t    = (unsigned short*)wsal(ws, (size_t)HID * KP * 2);
    unsigned short* W2t    = (unsigned short*)wsal(ws, (size_t)HID * HID * 2);

    p1_kernel<<<NPB, 256, 0, stream>>>(ei, outE, histG, W1, W1t, W2, W2t, E, nbuck);
    p2a_kernel<<<nbuck, NPB, 0, stream>>>(histG, totals);
    p3_part_kernel<<<NPB, 256, 0, stream>>>(ei, histG, totals, ebuf, E, nbuck);
    p4_sort_kernel<<<nbuck, 256, 0, stream>>>(ebuf, totals, csr, rowptr, dis,
                                              N, E, nbuck);
    xconv_kernel<<<(N * (KP / 2) + 255) / 256, 256, 0, stream>>>(x, dis, Xhs, N);

    const int ngf = (N + 15) / 16;

    // Layer 1: fused gather+gemm  (Xhs -> g2h)
    fused_kernel<true><<<ngf, 256, 0, stream>>>(
        (const uint4*)Xhs, rowptr, csr, W1t, b1, dis, g2h, N);

    // Layer 2: fused gather+gemm  (g2h -> outH)
    fused_kernel<false><<<ngf, 256, 0, stream>>>(
        (const uint4*)g2h, rowptr, csr, W2t, b2, dis, outH, N);
}

// Round 8
// 193.553 us; speedup vs baseline: 2.2991x; 1.0532x over previous
//
#include <hip/hip_runtime.h>
#include <hip/hip_bf16.h>

// GCN 2-layer, 7 launches. Buckets of 128 nodes (391 buckets).
//   p1    : bucket histogram + edge_index copy-out + W1/W2 transpose->bf16
//   p2a   : scan of per-partition bucket counts
//   p3    : partition edges into bucket-contiguous ebuf
//   p4    : per-bucket counting sort -> csr(ushort), rowptr, dis
//   xconv : Xhs = bf16(dis*X) [N][96] (zero-padded 89->96; 192B = 3 lines)
//   fused1: per 16-node block: gather rows -> LDS, then MFMA GEMM (K=96)
//           g2h = bf16( relu(d*(agg@W1t) + b1) * d )   [N][128]
//   fused2: same structure (K=128), out = relu( d*(agg@W2t) + b2 ) fp32
// 16 nodes/block (grid N/16=3125) => full occupancy during gather.
// All row operands bf16 (fp32 accumulation). Requires N < 65536.

#define HID 128
#define KIN 89
#define KP1 96    // layer-1 row: 96 bf16 = 192B = exactly 3 cache lines
#define KP2 128   // layer-2 row: 128 bf16 = 256B
#define BSH 7     // bucket = 128 nodes
#define BNODES 128
#define MAXBUCK 512   // capacity of bucket-indexed LDS/scan arrays
#define NPB 128       // partition blocks
#define P4CAP 3072    // staging capacity per bucket (mean ~2046, 5sd ~2270)

typedef __attribute__((ext_vector_type(8))) short bf16x8;
typedef __attribute__((ext_vector_type(4))) float f32x4;

static __device__ inline float2 unpack_bf16(unsigned v) {
    union { unsigned u; float f; } lo, hi;
    lo.u = v << 16;
    hi.u = v & 0xFFFF0000u;
    return make_float2(lo.f, hi.f);
}

static __device__ inline unsigned pack_bf16(float a, float b) {
    __hip_bfloat162 h = __float22bfloat162_rn(make_float2(a, b));
    return *reinterpret_cast<unsigned*>(&h);
}

static __device__ inline unsigned short f2bf(float v) {
    __hip_bfloat16 h = __float2bfloat16(v);
    return *reinterpret_cast<unsigned short*>(&h);
}

// ---- p1: histogram + edge copy + weight transposes ----
__global__ __launch_bounds__(256) void p1_kernel(
    const int* __restrict__ ei, float* __restrict__ outE,
    int* __restrict__ histG,
    const float* __restrict__ W1, unsigned short* __restrict__ W1t,
    const float* __restrict__ W2, unsigned short* __restrict__ W2t,
    int E, int nbuck)
{
    __shared__ int h[MAXBUCK];
    const int tid = threadIdx.x, blk = blockIdx.x;
    const int* src = ei;
    const int* dst = ei + E;
    for (int b = tid; b < nbuck; b += 256) h[b] = 0;

    // weight transposes spread over the grid's first 28672 threads
    int tg = blk * 256 + tid;
    if (tg < HID * KP1) {
        int n = tg / KP1, k = tg % KP1;
        W1t[tg] = f2bf(k < KIN ? W1[(size_t)k * HID + n] : 0.0f);
    } else {
        int t2 = tg - HID * KP1;
        if (t2 < HID * HID) {
            int n = t2 / HID, k = t2 % HID;
            W2t[t2] = f2bf(W2[(size_t)k * HID + n]);
        }
    }
    __syncthreads();

    const int chunk = (E + NPB - 1) / NPB;
    const int beg = blk * chunk, end = min(beg + chunk, E);
    for (int i = beg + tid; i < end; i += 256) {
        int d = dst[i];
        atomicAdd(&h[d >> BSH], 1);
        outE[i] = (float)src[i];
        outE[E + i] = (float)d;
    }
    __syncthreads();
    for (int b = tid; b < nbuck; b += 256) histG[b * NPB + blk] = h[b];
}

// ---- p2a: per-bucket exclusive scan of its NPB counts + totals ----
__global__ __launch_bounds__(NPB) void p2a_kernel(
    int* __restrict__ histG, int* __restrict__ totals)
{
    __shared__ int wsum[NPB / 64];
    const int b = blockIdx.x, tid = threadIdx.x, lane = tid & 63, wid = tid >> 6;
    int c = histG[b * NPB + tid];
    int s = c;
#pragma unroll
    for (int off = 1; off < 64; off <<= 1) {
        int t = __shfl_up(s, off, 64);
        if (lane >= off) s += t;
    }
    if (lane == 63) wsum[wid] = s;
    __syncthreads();
    if (tid == 0) {
        int a = 0;
#pragma unroll
        for (int w = 0; w < NPB / 64; ++w) { int t = wsum[w]; wsum[w] = a; a += t; }
    }
    __syncthreads();
    int excl = wsum[wid] + s - c;
    histG[b * NPB + tid] = excl;
    if (tid == NPB - 1) totals[b] = excl + c;
}

// In-block exclusive scan of totals[0..nbuck), nbuck <= 512, 256 threads.
static __device__ inline void scan_totals2(const int* __restrict__ totals,
                                           int* __restrict__ sexcl,
                                           int* __restrict__ wsum,
                                           int nbuck, int tid)
{
    const int lane = tid & 63, wid = tid >> 6;
    const int i0 = 2 * tid, i1 = 2 * tid + 1;
    int t0 = (i0 < nbuck) ? totals[i0] : 0;
    int t1 = (i1 < nbuck) ? totals[i1] : 0;
    int p = t0 + t1;
    int s = p;
#pragma unroll
    for (int off = 1; off < 64; off <<= 1) {
        int t = __shfl_up(s, off, 64);
        if (lane >= off) s += t;
    }
    if (lane == 63) wsum[wid] = s;
    __syncthreads();
    if (tid == 0) {
        int a = 0;
#pragma unroll
        for (int w = 0; w < 4; ++w) { int t = wsum[w]; wsum[w] = a; a += t; }
    }
    __syncthreads();
    int excl = wsum[wid] + s - p;
    sexcl[i0] = excl;
    sexcl[i1] = excl + t0;
}

// ---- p3: partition edges into bucket-contiguous ebuf ----
__global__ __launch_bounds__(256) void p3_part_kernel(
    const int* __restrict__ ei, const int* __restrict__ histG,
    const int* __restrict__ totals, unsigned* __restrict__ ebuf,
    int E, int nbuck)
{
    __shared__ int cur[MAXBUCK];
    __shared__ int wsum[4];
    const int tid = threadIdx.x, blk = blockIdx.x;
    const int* src = ei;
    const int* dst = ei + E;
    scan_totals2(totals, cur, wsum, nbuck, tid);   // cur[b] = bucket base
    __syncthreads();
    for (int b = tid; b < nbuck; b += 256) cur[b] += histG[b * NPB + blk];
    const int chunk = (E + NPB - 1) / NPB;
    const int beg = blk * chunk, end = min(beg + chunk, E);
    __syncthreads();
    for (int i = beg + tid; i < end; i += 256) {
        int d = dst[i];
        int b = d >> BSH;
        int pos = atomicAdd(&cur[b], 1);
        ebuf[pos] = ((unsigned)(d & (BNODES - 1)) << 16) | (unsigned)src[i];
    }
}

// ---- p4: per-bucket sort -> csr, rowptr, dis ----
__global__ __launch_bounds__(256) void p4_sort_kernel(
    const unsigned* __restrict__ ebuf, const int* __restrict__ totals,
    unsigned short* __restrict__ csr, int* __restrict__ rowptr,
    float* __restrict__ dis, int N, int E, int nbuck)
{
    __shared__ int counts[BNODES];
    __shared__ int cursor[BNODES];
    __shared__ int sbase[MAXBUCK];
    __shared__ int wsum[4];
    __shared__ int w2[2];
    __shared__ unsigned short staging[P4CAP];
    const int b = blockIdx.x, tid = threadIdx.x, lane = tid & 63, wid = tid >> 6;

    scan_totals2(totals, sbase, wsum, nbuck, tid);
    __syncthreads();
    const int gbase = sbase[b];
    const int cnt = totals[b];

    if (tid < BNODES) counts[tid] = 0;
    __syncthreads();
    for (int i = tid; i < cnt; i += 256)
        atomicAdd(&counts[ebuf[gbase + i] >> 16], 1);
    __syncthreads();

    // exclusive scan of BNODES=128 counts (first 2 waves)
    int c = 0, s = 0;
    if (tid < BNODES) {
        c = counts[tid];
        s = c;
#pragma unroll
        for (int off = 1; off < 64; off <<= 1) {
            int t = __shfl_up(s, off, 64);
            if (lane >= off) s += t;
        }
        if (lane == 63) w2[wid] = s;
    }
    __syncthreads();
    if (tid == 0) { int t = w2[0]; w2[0] = 0; w2[1] = t; }
    __syncthreads();
    if (tid < BNODES) {
        int excl = w2[wid] + s - c;
        cursor[tid] = excl;
        int node = b * BNODES + tid;
        if (node < N) {
            rowptr[node] = gbase + excl;
            dis[node] = rsqrtf(1.0f + (float)c);
        }
    }
    if (b == 0 && tid == 0) rowptr[N] = E;
    __syncthreads();

    if (cnt <= P4CAP) {
        for (int i = tid; i < cnt; i += 256) {
            unsigned v = ebuf[gbase + i];
            int pos = atomicAdd(&cursor[v >> 16], 1);
            staging[pos] = (unsigned short)(v & 0xFFFFu);
        }
        __syncthreads();
        for (int i = tid; i < cnt; i += 256)
            csr[gbase + i] = staging[i];
    } else {
        for (int i = tid; i < cnt; i += 256) {
            unsigned v = ebuf[gbase + i];
            int pos = atomicAdd(&cursor[v >> 16], 1);
            csr[gbase + pos] = (unsigned short)(v & 0xFFFFu);
        }
    }
}

// ---- xconv: Xhs = bf16(dis * X) [N][KP1], zero-padded cols 89..95 ----
__global__ __launch_bounds__(256) void xconv_kernel(
    const float* __restrict__ X, const float* __restrict__ dis,
    unsigned* __restrict__ Xhs, int N)
{
    int t = blockIdx.x * 256 + threadIdx.x;
    if (t >= N * (KP1 / 2)) return;
    int n = t / (KP1 / 2), c = t % (KP1 / 2);
    float d = dis[n];
    const float* xr = X + (size_t)n * KIN;
    float a = (2 * c     < KIN) ? d * xr[2 * c]     : 0.0f;
    float b = (2 * c + 1 < KIN) ? d * xr[2 * c + 1] : 0.0f;
    Xhs[t] = pack_bf16(a, b);
}

// ---- fused: gather 16 nodes -> LDS (bf16), then MFMA GEMM from LDS ----
// Gather: one pass, 4 waves x 4 nodes/wave; 16-lane group per node, lane
// sl reads row chunk min(sl, ROWU4-1) (dup lanes touch no extra lines);
// 4 independent csr->row chains per wave.
// GEMM: 4 waves share the block's 16 rows (B-frag from LDS); wave w
// computes col tiles {2w, 2w+1} (A-frag = weights from global, L1/L2-hot).
//   LAYER1: store bf16( relu(d*acc + b) * d )   (pre-scaled rows for layer 2)
//   LAYER2: store fp32( relu(d*acc + b) )
template<int KPA, bool LAYER1>
__global__ __launch_bounds__(256) void fused_kernel(
    const uint4* __restrict__ rows, const int* __restrict__ rowptr,
    const unsigned short* __restrict__ csr,
    const unsigned short* __restrict__ Wt, const float* __restrict__ bias,
    const float* __restrict__ dis, void* __restrict__ outp, int N)
{
    constexpr int ROWU4 = KPA / 8;                 // uint4 chunks per row
    constexpr int LDSP  = (KPA == 96) ? 104 : 136; // row stride (ushorts)
    __shared__ unsigned short lds_a[16][LDSP];
    const int tid  = threadIdx.x;
    const int wave = tid >> 6;
    const int lane = tid & 63;
    const int sub  = (lane >> 4) & 3;    // node slot within wave (0..3)
    const int sl   = lane & 15;          // 16B chunk within row
    const int slc  = (ROWU4 == 16) ? sl : min(sl, ROWU4 - 1);
    const bool act = (ROWU4 == 16) || (sl < ROWU4);
    const int blk0 = blockIdx.x * 16;

    // ---- gather phase: wave w fills LDS rows w*4 .. w*4+3 ----
    {
        const int lrow = wave * 4 + sub;
        const int node = blk0 + lrow;
        const bool valid = node < N;
        const int cn = valid ? node : N - 1;

        // self row (added once)
        uint4 sv = rows[(size_t)cn * ROWU4 + slc];
        float a0, a1, a2, a3, a4, a5, a6, a7;
        {
            float2 q;
            q = unpack_bf16(sv.x); a0 = q.x; a1 = q.y;
            q = unpack_bf16(sv.y); a2 = q.x; a3 = q.y;
            q = unpack_bf16(sv.z); a4 = q.x; a5 = q.y;
            q = unpack_bf16(sv.w); a6 = q.x; a7 = q.y;
        }

        int beg = rowptr[cn];
        int end = valid ? rowptr[cn + 1] : beg;
        int j = beg;
        for (; j + 4 <= end; j += 4) {   // 4 rows in flight per chain
            int r0 = csr[j], r1 = csr[j + 1], r2 = csr[j + 2], r3 = csr[j + 3];
            uint4 v0 = rows[(size_t)r0 * ROWU4 + slc];
            uint4 v1 = rows[(size_t)r1 * ROWU4 + slc];
            uint4 v2 = rows[(size_t)r2 * ROWU4 + slc];
            uint4 v3 = rows[(size_t)r3 * ROWU4 + slc];
            float2 q;
            q = unpack_bf16(v0.x); a0 += q.x; a1 += q.y;
            q = unpack_bf16(v0.y); a2 += q.x; a3 += q.y;
            q = unpack_bf16(v0.z); a4 += q.x; a5 += q.y;
            q = unpack_bf16(v0.w); a6 += q.x; a7 += q.y;
            q = unpack_bf16(v1.x); a0 += q.x; a1 += q.y;
            q = unpack_bf16(v1.y); a2 += q.x; a3 += q.y;
            q = unpack_bf16(v1.z); a4 += q.x; a5 += q.y;
            q = unpack_bf16(v1.w); a6 += q.x; a7 += q.y;
            q = unpack_bf16(v2.x); a0 += q.x; a1 += q.y;
            q = unpack_bf16(v2.y); a2 += q.x; a3 += q.y;
            q = unpack_bf16(v2.z); a4 += q.x; a5 += q.y;
            q = unpack_bf16(v2.w); a6 += q.x; a7 += q.y;
            q = unpack_bf16(v3.x); a0 += q.x; a1 += q.y;
            q = unpack_bf16(v3.y); a2 += q.x; a3 += q.y;
            q = unpack_bf16(v3.z); a4 += q.x; a5 += q.y;
            q = unpack_bf16(v3.w); a6 += q.x; a7 += q.y;
        }
        for (; j < end; ++j) {
            int r = csr[j];
            uint4 v = rows[(size_t)r * ROWU4 + slc];
            float2 q;
            q = unpack_bf16(v.x); a0 += q.x; a1 += q.y;
            q = unpack_bf16(v.y); a2 += q.x; a3 += q.y;
            q = unpack_bf16(v.z); a4 += q.x; a5 += q.y;
            q = unpack_bf16(v.w); a6 += q.x; a7 += q.y;
        }

        if (act) {
            uint4 pk = make_uint4(pack_bf16(a0, a1), pack_bf16(a2, a3),
                                  pack_bf16(a4, a5), pack_bf16(a6, a7));
            *(uint4*)&lds_a[lrow][sl * 8] = pk;
        }
    }
    __syncthreads();

    // ---- gemm phase: wave w -> col tiles {2w, 2w+1} over the 16 rows ----
    const int m    = lane & 15;
    const int quad = lane >> 4;
    const int node = blk0 + m;

    f32x4 acc[2];
    acc[0] = (f32x4){0.0f, 0.0f, 0.0f, 0.0f};
    acc[1] = (f32x4){0.0f, 0.0f, 0.0f, 0.0f};

    const unsigned short* arp = &lds_a[m][0];

#pragma unroll
    for (int c = 0; c < KPA / 32; ++c) {
        const int k0 = c * 32 + quad * 8;
        bf16x8 nv = *(const bf16x8*)(arp + k0);                      // B-frag (LDS)
#pragma unroll
        for (int t2 = 0; t2 < 2; ++t2) {
            const int t = wave * 2 + t2;
            bf16x8 wv = *(const bf16x8*)(Wt + (size_t)(t * 16 + m) * KPA + k0);  // A-frag
            acc[t2] = __builtin_amdgcn_mfma_f32_16x16x32_bf16(wv, nv, acc[t2], 0, 0, 0);
        }
    }

    if (node < N) {
        const float dv = dis[node];
#pragma unroll
        for (int t2 = 0; t2 < 2; ++t2) {
            const int col0 = (wave * 2 + t2) * 16 + quad * 4;
            float4 bb = *(const float4*)&bias[col0];
            float r0 = fmaxf(fmaf(dv, acc[t2][0], bb.x), 0.0f);
            float r1 = fmaxf(fmaf(dv, acc[t2][1], bb.y), 0.0f);
            float r2 = fmaxf(fmaf(dv, acc[t2][2], bb.z), 0.0f);
            float r3 = fmaxf(fmaf(dv, acc[t2][3], bb.w), 0.0f);
            if (LAYER1) {
                uint2 u;
                u.x = pack_bf16(r0 * dv, r1 * dv);
                u.y = pack_bf16(r2 * dv, r3 * dv);
                *(uint2*)((unsigned short*)outp + (size_t)node * HID + col0) = u;
            } else {
                float4 r = make_float4(r0, r1, r2, r3);
                *(float4*)((float*)outp + (size_t)node * HID + col0) = r;
            }
        }
    }
}

// ---------------- launch ----------------

static inline char* wsal(char*& p, size_t n) {
    uintptr_t q = ((uintptr_t)p + 255) & ~(uintptr_t)255;
    char* r = (char*)q;
    p = r + n;
    return r;
}

extern "C" void kernel_launch(void* const* d_in, const int* in_sizes, int n_in,
                              void* d_out, int out_size, void* d_ws, size_t ws_size,
                              hipStream_t stream) {
    const float* x  = (const float*)d_in[0];
    const int*   ei = (const int*)d_in[1];
    const float* W1 = (const float*)d_in[2];
    const float* b1 = (const float*)d_in[3];
    const float* W2 = (const float*)d_in[4];
    const float* b2 = (const float*)d_in[5];

    const int N = in_sizes[0] / KIN;  // 50000  (< 65536 required)
    const int E = in_sizes[1] / 2;    // 800000
    const int nbuck = (N + BNODES - 1) >> BSH;   // 391 (<= MAXBUCK)

    float* out  = (float*)d_out;
    float* outH = out;                      // [N,128] final fp32 output
    float* outE = out + (size_t)N * HID;    // [2,E] edge_index as float

    char* ws = (char*)d_ws;
    int*            histG  = (int*)wsal(ws, (size_t)MAXBUCK * NPB * 4);
    int*            totals = (int*)wsal(ws, MAXBUCK * 4);
    int*            rowptr = (int*)wsal(ws, (size_t)(N + 1) * 4);
    float*          dis    = (float*)wsal(ws, (size_t)N * 4);
    unsigned*       ebuf   = (unsigned*)wsal(ws, (size_t)E * 4);
    unsigned short* csr    = (unsigned short*)wsal(ws, (size_t)E * 2);
    unsigned*       Xhs    = (unsigned*)wsal(ws, (size_t)N * (KP1 / 2) * 4);
    unsigned short* g2h    = (unsigned short*)wsal(ws, (size_t)N * HID * 2);
    unsigned short* W1t    = (unsigned short*)wsal(ws, (size_t)HID * KP1 * 2);
    unsigned short* W2t    = (unsigned short*)wsal(ws, (size_t)HID * HID * 2);

    p1_kernel<<<NPB, 256, 0, stream>>>(ei, outE, histG, W1, W1t, W2, W2t, E, nbuck);
    p2a_kernel<<<nbuck, NPB, 0, stream>>>(histG, totals);
    p3_part_kernel<<<NPB, 256, 0, stream>>>(ei, histG, totals, ebuf, E, nbuck);
    p4_sort_kernel<<<nbuck, 256, 0, stream>>>(ebuf, totals, csr, rowptr, dis,
                                              N, E, nbuck);
    xconv_kernel<<<(N * (KP1 / 2) + 255) / 256, 256, 0, stream>>>(x, dis, Xhs, N);

    const int ngf = (N + 15) / 16;

    // Layer 1: fused gather+gemm  (Xhs [N][96] -> g2h [N][128])
    fused_kernel<KP1, true><<<ngf, 256, 0, stream>>>(
        (const uint4*)Xhs, rowptr, csr, W1t, b1, dis, g2h, N);

    // Layer 2: fused gather+gemm  (g2h [N][128] -> outH fp32)
    fused_kernel<KP2, false><<<ngf, 256, 0, stream>>>(
        (const uint4*)g2h, rowptr, csr, W2t, b2, dis, outH, N);
}